// Round 16
// baseline (2077.223 us; speedup 1.0000x reference)
//
#include <hip/hip_runtime.h>
#include <cmath>

#define B_    8
#define INS_  32
#define OUTS_ 64
#define REF_  8
#define H_    256
#define NH_   8
#define DH_   32
#define NL_   6
#define DFF_  1024
#define N_    4096
#define M_    (B_*N_)      // 32768 rows
#define BUF   8388608ull   // M*H elements

typedef unsigned short u16;
typedef unsigned int   u32;
typedef __attribute__((ext_vector_type(8))) short  bf16x8;
typedef __attribute__((ext_vector_type(4))) float  f32x4;
typedef __attribute__((ext_vector_type(4))) unsigned short u16x4;

struct bfpair { u16 hi, lo; };

__device__ __forceinline__ float gelu_f(float x){
    return 0.5f * x * (1.0f + erff(x * 0.70710678118654752f));
}
__device__ __forceinline__ u16 f2b(float f){
    union { float f; u32 u; } v; v.f = f;
    u32 r = v.u + 0x7fffu + ((v.u >> 16) & 1u);
    return (u16)(r >> 16);
}
__device__ __forceinline__ float b2f(u16 b){
    union { u32 u; float f; } v; v.u = ((u32)b) << 16;
    return v.f;
}
__device__ __forceinline__ bfpair fsplit(float x){
    bfpair p;
    p.hi = f2b(x);
    p.lo = f2b(x - b2f(p.hi));
    return p;
}

// ---------------------------------------------------------------------------
// Weight convert+transpose+split: out[l*lstride + n*Kpad + k] = split(in[l][k][n])
// ---------------------------------------------------------------------------
__global__ __launch_bounds__(256) void tconv_kernel(const float* __restrict__ in,
                                                    u16* __restrict__ oh,
                                                    u16* __restrict__ ol,
                                                    int K, int N, int Kpad, int nl,
                                                    int lstride)
{
    int idx = blockIdx.x * 256 + threadIdx.x;
    int per = N * Kpad;
    if (idx >= nl * per) return;
    int l = idx / per;
    int rem = idx - l * per;
    int n = rem / Kpad;
    int k = rem - n * Kpad;
    float v = (k < K) ? in[(size_t)l * K * N + (size_t)k * N + n] : 0.0f;
    bfpair p = fsplit(v);
    size_t o = (size_t)l * lstride + (size_t)n * Kpad + k;
    oh[o] = p.hi; ol[o] = p.lo;
}

// ---------------------------------------------------------------------------
// Concatenate kn||vn affines per layer -> [NL][512] fp32
// ---------------------------------------------------------------------------
__global__ __launch_bounds__(256) void lnfold_kernel(const float* __restrict__ kg,
                                                     const float* __restrict__ kb,
                                                     const float* __restrict__ vg,
                                                     const float* __restrict__ vb,
                                                     float* __restrict__ lng,
                                                     float* __restrict__ lnb)
{
    int idx = blockIdx.x * 256 + threadIdx.x;
    if (idx >= NL_ * 512) return;
    int l = idx >> 9, c = idx & 511;
    if (c < 256) { lng[idx] = kg[l * 256 + c];       lnb[idx] = kb[l * 256 + c]; }
    else         { lng[idx] = vg[l * 256 + c - 256]; lnb[idx] = vb[l * 256 + c - 256]; }
}

// ---------------------------------------------------------------------------
// fx builder -> split bf16 [M, 96] (cols 0..64 real, rest zero)
// ---------------------------------------------------------------------------
__global__ __launch_bounds__(256) void fx_kernel(const float* __restrict__ x,
                                                 u16* __restrict__ fh,
                                                 u16* __restrict__ fl)
{
    int idx = blockIdx.x * 256 + threadIdx.x;
    const int total = M_ * 96;
    if (idx >= total) return;
    int f   = idx % 96;
    int row = idx / 96;
    int n   = row % N_;
    int b   = row / N_;
    int gi = n >> 6, gj = n & 63;
    float v = 0.0f;
    if (f == 0) {
        float ci = gi * (31.0f / 63.0f);
        float cj = gj * (31.0f / 63.0f);
        int i0 = (int)floorf(ci); int i1 = min(i0 + 1, 31);
        int j0 = (int)floorf(cj); int j1 = min(j0 + 1, 31);
        float wi = ci - (float)i0, wj = cj - (float)j0;
        const float* xb = x + (size_t)b * INS_ * INS_ * 3 + 2;  // channel 2
        float v00 = xb[(i0 * 32 + j0) * 3];
        float v01 = xb[(i0 * 32 + j1) * 3];
        float v10 = xb[(i1 * 32 + j0) * 3];
        float v11 = xb[(i1 * 32 + j1) * 3];
        float r0 = v00 * (1.0f - wi) + v10 * wi;
        float r1 = v01 * (1.0f - wi) + v11 * wi;
        v = r0 * (1.0f - wj) + r1 * wj;
    } else if (f < 65) {
        int r = f - 1;
        int ri = r >> 3, rj = r & 7;
        float dx = gi * (1.0f / 63.0f) - ri * (1.0f / 7.0f);
        float dy = gj * (1.0f / 63.0f) - rj * (1.0f / 7.0f);
        v = sqrtf(dx * dx + dy * dy);
    }
    bfpair p = fsplit(v);
    fh[idx] = p.hi; fl[idx] = p.lo;
}

// ---------------------------------------------------------------------------
// Split-bf16 MFMA GEMM, 2-phase K-loop with COUNTED vmcnt (T3+T4):
// raw s_barrier + vmcnt(LPS) keeps one stage of global_load_lds in flight
// across the barrier (no full drain). Bit-identical arithmetic.
// Per step: vmcnt(LPS)|bar|SGB -> ds-reads -> lgkm(0)|SGB|bar|SGB ->
//           stage(t+2) -> MFMA.
// TERMS=3: hi*hi + lo*hi + hi*lo (~fp32).  TERMS=2: hi*hi + lo*hi.
// EPI: 0 = split store, 1 = gelu->split store, 2 = f32 +=, 3 = f32 store +b2,
//      4 = fused per-head LN (DH=32) -> split store (kv path; BN=128 only).
// bstride: elements to advance Bh/Bl per 4096 A-rows (batched B); 0 = shared.
// XCD-aware chunked block swizzle (all grids divisible by 8).
// ---------------------------------------------------------------------------
template<int EPI, int BN, int TERMS>
__global__ __launch_bounds__(256) void gemm_split(const u16* __restrict__ Ah,
                                                  const u16* __restrict__ Al,
                                                  const u16* __restrict__ Bh,
                                                  const u16* __restrict__ Bl,
                                                  float* __restrict__ Cf,
                                                  u16* __restrict__ Ch,
                                                  u16* __restrict__ Cl,
                                                  const float* __restrict__ bias,
                                                  const float* __restrict__ bias2,
                                                  const float* __restrict__ lng,
                                                  const float* __restrict__ lnb,
                                                  int M, int Nn, int K, int bstride)
{
    constexpr int NREP = BN / 32;           // frags per wave in N
    constexpr int BROUNDS = BN / 64;        // B staging rounds
    // global_load_lds issued per stage() call (per thread):
    constexpr int LPS = 2 * (TERMS >= 2 ? 2 : 1) + BROUNDS * (TERMS == 3 ? 2 : 1);
    __shared__ u16 AsH[2][4096];
    __shared__ u16 BsH[2][BN * 32];
    __shared__ u16 AsL[TERMS >= 2 ? 2 : 1][TERMS >= 2 ? 4096 : 1];
    __shared__ u16 BsL[TERMS == 3 ? 2 : 1][TERMS == 3 ? BN * 32 : 1];
    const int tid = threadIdx.x;
    const int nwgx = gridDim.x;
    const int nwg  = nwgx * gridDim.y;
    const int bid  = blockIdx.y * nwgx + blockIdx.x;
    const int swz  = (bid & 7) * (nwg >> 3) + (bid >> 3);
    const int bm = (swz / nwgx) * 128;
    const int bn = (swz % nwgx) * BN;
    const u16* BhB = Bh + (size_t)(bm >> 12) * bstride;
    const u16* BlB = Bl + (size_t)(bm >> 12) * bstride;
    const int l  = tid & 63;
    const int w  = tid >> 6;
    const int wr = w >> 1, wc = w & 1;
    const int lrow = l & 15;
    const int kh   = l >> 4;       // 0..3

    auto stage = [&](int k0, int s) {
        #pragma unroll
        for (int i = 0; i < 2; ++i) {       // A tile: 128x32
            int L = i * 256 + tid;
            int row = L >> 2, ch = L & 3;
            size_t goffA = (size_t)(bm + row) * K + k0 + ch * 8;
            __builtin_amdgcn_global_load_lds(
                (const __attribute__((address_space(1))) void*)(Ah + goffA),
                (__attribute__((address_space(3))) void*)(&AsH[s][L * 8]), 16, 0, 0);
            if constexpr (TERMS >= 2)
                __builtin_amdgcn_global_load_lds(
                    (const __attribute__((address_space(1))) void*)(Al + goffA),
                    (__attribute__((address_space(3))) void*)(&AsL[s][L * 8]), 16, 0, 0);
        }
        #pragma unroll
        for (int i = 0; i < BROUNDS; ++i) { // B tile: BNx32
            int L = i * 256 + tid;
            int row = L >> 2, ch = L & 3;
            size_t goffB = (size_t)(bn + row) * K + k0 + ch * 8;
            __builtin_amdgcn_global_load_lds(
                (const __attribute__((address_space(1))) void*)(BhB + goffB),
                (__attribute__((address_space(3))) void*)(&BsH[s][L * 8]), 16, 0, 0);
            if constexpr (TERMS == 3)
                __builtin_amdgcn_global_load_lds(
                    (const __attribute__((address_space(1))) void*)(BlB + goffB),
                    (__attribute__((address_space(3))) void*)(&BsL[s][L * 8]), 16, 0, 0);
        }
    };

    f32x4 acc[4][NREP];
    #pragma unroll
    for (int m = 0; m < 4; ++m)
        #pragma unroll
        for (int n = 0; n < NREP; ++n)
            acc[m][n] = (f32x4){0.0f, 0.0f, 0.0f, 0.0f};

    const int nk = K >> 5;
    stage(0, 0);
    if (nk > 1) stage(32, 1);
    int cur = 0;
    for (int t = 0; t < nk; ++t) {
        // stage(t) must be complete; stage(t+1) (if issued) may remain in flight.
        if (t + 1 < nk) {
            asm volatile("s_waitcnt vmcnt(%0)" :: "n"(LPS) : "memory");
        } else {
            asm volatile("s_waitcnt vmcnt(0)" ::: "memory");
        }
        __builtin_amdgcn_s_barrier();
        __builtin_amdgcn_sched_barrier(0);      // ds-reads stay below barrier

        bf16x8 afh[4], afl[4], bfh[NREP], bfl[NREP];
        #pragma unroll
        for (int m = 0; m < 4; ++m) {
            int off = (wr * 64 + m * 16 + lrow) * 32 + kh * 8;
            afh[m] = *(const bf16x8*)(&AsH[cur][off]);
            if constexpr (TERMS >= 2) afl[m] = *(const bf16x8*)(&AsL[cur][off]);
        }
        #pragma unroll
        for (int n = 0; n < NREP; ++n) {
            int off = (wc * (BN / 2) + n * 16 + lrow) * 32 + kh * 8;
            bfh[n] = *(const bf16x8*)(&BsH[cur][off]);
            if constexpr (TERMS == 3) bfl[n] = *(const bf16x8*)(&BsL[cur][off]);
        }
        asm volatile("s_waitcnt lgkmcnt(0)" ::: "memory");  // my reads landed
        __builtin_amdgcn_sched_barrier(0);
        __builtin_amdgcn_s_barrier();           // all waves done reading buf[cur]
        __builtin_amdgcn_sched_barrier(0);      // stage stays below barrier

        if (t + 2 < nk) stage((t + 2) << 5, cur);   // overwrite just-read buffer

        #pragma unroll
        for (int m = 0; m < 4; ++m)
            #pragma unroll
            for (int n = 0; n < NREP; ++n) {
                acc[m][n] = __builtin_amdgcn_mfma_f32_16x16x32_bf16(afh[m], bfh[n], acc[m][n], 0, 0, 0);
                if constexpr (TERMS >= 2)
                    acc[m][n] = __builtin_amdgcn_mfma_f32_16x16x32_bf16(afl[m], bfh[n], acc[m][n], 0, 0, 0);
                if constexpr (TERMS == 3)
                    acc[m][n] = __builtin_amdgcn_mfma_f32_16x16x32_bf16(afh[m], bfl[n], acc[m][n], 0, 0, 0);
            }
        cur ^= 1;
    }

    const int row0 = bm + wr * 64;
    const int col0 = bn + wc * (BN / 2);

    if constexpr (EPI == 4) {
        // fused per-head LayerNorm over DH=32 (stats via 16-lane shfl groups)
        #pragma unroll
        for (int m = 0; m < 4; ++m) {
            #pragma unroll
            for (int j = 0; j < 4; ++j) {
                int r = row0 + m * 16 + kh * 4 + j;
                #pragma unroll
                for (int hp = 0; hp < NREP / 2; ++hp) {
                    float a0 = acc[m][2 * hp + 0][j];
                    float a1 = acc[m][2 * hp + 1][j];
                    float s = a0 + a1;
                    s += __shfl_xor(s, 1); s += __shfl_xor(s, 2);
                    s += __shfl_xor(s, 4); s += __shfl_xor(s, 8);
                    float mean = s * (1.0f / 32.0f);
                    float d0 = a0 - mean, d1 = a1 - mean;
                    float q = d0 * d0 + d1 * d1;
                    q += __shfl_xor(q, 1); q += __shfl_xor(q, 2);
                    q += __shfl_xor(q, 4); q += __shfl_xor(q, 8);
                    float rstd = rsqrtf(q * (1.0f / 32.0f) + 1e-5f);
                    #pragma unroll
                    for (int t = 0; t < 2; ++t) {
                        int n = 2 * hp + t;
                        int col = col0 + n * 16 + lrow;
                        float dd = t ? d1 : d0;
                        float o = dd * rstd * lng[col] + lnb[col];
                        bfpair p = fsplit(o);
                        size_t idx = (size_t)r * Nn + col;
                        Ch[idx] = p.hi; Cl[idx] = p.lo;
                    }
                }
            }
        }
        return;
    }

    #pragma unroll
    for (int m = 0; m < 4; ++m) {
        #pragma unroll
        for (int n = 0; n < NREP; ++n) {
            int col = col0 + n * 16 + lrow;
            float bv = bias ? bias[col] : 0.0f;
            if (EPI == 3) bv += bias2[col];
            #pragma unroll
            for (int j = 0; j < 4; ++j) {
                int r = row0 + m * 16 + kh * 4 + j;
                float v = acc[m][n][j] + bv;
                size_t idx = (size_t)r * Nn + col;
                if (EPI == 0) {
                    bfpair p = fsplit(v);
                    Ch[idx] = p.hi; Cl[idx] = p.lo;
                } else if (EPI == 1) {
                    bfpair p = fsplit(gelu_f(v));
                    Ch[idx] = p.hi; Cl[idx] = p.lo;
                } else if (EPI == 2) {
                    Cf[idx] += v;
                } else {
                    Cf[idx] = v;
                }
            }
        }
    }
}

// ---------------------------------------------------------------------------
// Dual LayerNorm over H=256 (fp32 in, split bf16 out). o2h==nullptr -> single.
// ---------------------------------------------------------------------------
__global__ __launch_bounds__(256) void ln_dual_kernel(const float* __restrict__ h,
                                                      u16* __restrict__ o1h,
                                                      u16* __restrict__ o1l,
                                                      u16* __restrict__ o2h,
                                                      u16* __restrict__ o2l,
                                                      const float* __restrict__ g1,
                                                      const float* __restrict__ b1,
                                                      const float* __restrict__ g2,
                                                      const float* __restrict__ b2)
{
    int row  = blockIdx.x * 4 + (threadIdx.x >> 6);
    int lane = threadIdx.x & 63;
    const float4 v = ((const float4*)(h + (size_t)row * H_))[lane];
    float s = v.x + v.y + v.z + v.w;
    #pragma unroll
    for (int m = 1; m < 64; m <<= 1) s += __shfl_xor(s, m, 64);
    float mean = s * (1.0f / H_);
    float dx = v.x - mean, dy = v.y - mean, dz = v.z - mean, dw = v.w - mean;
    float sq = dx * dx + dy * dy + dz * dz + dw * dw;
    #pragma unroll
    for (int m = 1; m < 64; m <<= 1) sq += __shfl_xor(sq, m, 64);
    float rstd = rsqrtf(sq * (1.0f / H_) + 1e-5f);

    float4 G = ((const float4*)g1)[lane];
    float4 Bv = ((const float4*)b1)[lane];
    u16x4 oh, ol;
    bfpair p0 = fsplit(dx * rstd * G.x + Bv.x);
    bfpair p1 = fsplit(dy * rstd * G.y + Bv.y);
    bfpair p2 = fsplit(dz * rstd * G.z + Bv.z);
    bfpair p3 = fsplit(dw * rstd * G.w + Bv.w);
    oh.x = p0.hi; ol.x = p0.lo;
    oh.y = p1.hi; ol.y = p1.lo;
    oh.z = p2.hi; ol.z = p2.lo;
    oh.w = p3.hi; ol.w = p3.lo;
    ((u16x4*)(o1h + (size_t)row * H_))[lane] = oh;
    ((u16x4*)(o1l + (size_t)row * H_))[lane] = ol;
    if (o2h) {
        G = ((const float4*)g2)[lane];
        Bv = ((const float4*)b2)[lane];
        p0 = fsplit(dx * rstd * G.x + Bv.x);
        p1 = fsplit(dy * rstd * G.y + Bv.y);
        p2 = fsplit(dz * rstd * G.z + Bv.z);
        p3 = fsplit(dw * rstd * G.w + Bv.w);
        oh.x = p0.hi; ol.x = p0.lo;
        oh.y = p1.hi; ol.y = p1.lo;
        oh.z = p2.hi; ol.z = p2.lo;
        oh.w = p3.hi; ol.w = p3.lo;
        ((u16x4*)(o2h + (size_t)row * H_))[lane] = oh;
        ((u16x4*)(o2l + (size_t)row * H_))[lane] = ol;
    }
}

// ---------------------------------------------------------------------------
// ctx partials over fused kv buffer: ctxp[split][b*NH+h][32][32]
// 64-row LDS staging (16 barriers/block); per-thread row order unchanged.
// ---------------------------------------------------------------------------
__global__ __launch_bounds__(256) void ctx_partial_kernel(const u16* __restrict__ kvh,
                                                          const u16* __restrict__ kvl,
                                                          float* __restrict__ ctxp)
{
    int bh = blockIdx.x;            // 0..63
    int split = blockIdx.y;         // 0..7
    int b = bh >> 3, hd = bh & 7;
    __shared__ float kc[64][32], vc[64][32];
    int tid = threadIdx.x;
    int d  = tid >> 3;
    int e0 = (tid & 7) * 4;
    float a0 = 0, a1 = 0, a2 = 0, a3 = 0;
    int nbase = split * 512;
    for (int it = 0; it < 8; ++it) {
        #pragma unroll
        for (int i = 0; i < 8; ++i) {
            int elem = i * 256 + tid;
            int row = elem >> 5, col = elem & 31;
            size_t off = ((size_t)(b * N_ + nbase + it * 64 + row)) * 512 + hd * 32 + col;
            kc[row][col] = b2f(kvh[off]) + b2f(kvl[off]);
            vc[row][col] = b2f(kvh[off + 256]) + b2f(kvl[off + 256]);
        }
        __syncthreads();
        #pragma unroll
        for (int r = 0; r < 64; ++r) {
            float kd = kc[r][d];
            a0 += kd * vc[r][e0 + 0];
            a1 += kd * vc[r][e0 + 1];
            a2 += kd * vc[r][e0 + 2];
            a3 += kd * vc[r][e0 + 3];
        }
        __syncthreads();
    }
    float* out = ctxp + ((size_t)(split * 64 + bh)) * 1024 + d * 32 + e0;
    out[0] = a0; out[1] = a1; out[2] = a2; out[3] = a3;
}

// ---------------------------------------------------------------------------
// compose1 (fused ctx-reduce): G[b][hd*32+d][j] =
//   sum_e ( (1/N) * sum_sp ctxp[sp][b*8+hd][d][e] ) * Wo[hd*32+e][j]
// ---------------------------------------------------------------------------
__global__ __launch_bounds__(256) void compose1_kernel(const float* __restrict__ ctxp,
                                                       const float* __restrict__ Wo,
                                                       float* __restrict__ G)
{
    int b  = blockIdx.x >> 3;
    int hd = blockIdx.x & 7;
    __shared__ float cl[32][32];
    __shared__ float wl[32][256];
    int tid = threadIdx.x;
    {
        const float* src = ctxp + ((size_t)(b * 8 + hd)) * 1024;
        #pragma unroll
        for (int i = 0; i < 4; ++i) {
            float s = 0.0f;
            #pragma unroll
            for (int sp = 0; sp < 8; ++sp)
                s += src[(size_t)sp * 65536 + tid + 256 * i];
            ((float*)cl)[tid + 256 * i] = s * (1.0f / N_);
        }
        #pragma unroll
        for (int i = 0; i < 32; ++i)
            wl[i][tid] = Wo[(size_t)(hd * 32 + i) * 256 + tid];
    }
    __syncthreads();
    int j = tid;
    for (int d = 0; d < 32; ++d) {
        float s = 0.0f;
        #pragma unroll
        for (int e = 0; e < 32; ++e) s += cl[d][e] * wl[e][j];
        G[((size_t)b * 256 + hd * 32 + d) * 256 + j] = s;
    }
}

// ---------------------------------------------------------------------------
// compose2: F_t[b][j][i] = split( sum_m Wq[i][m] * G[b][m][j] )
// ---------------------------------------------------------------------------
__global__ __launch_bounds__(256) void compose2_kernel(const float* __restrict__ Wq,
                                                       const float* __restrict__ G,
                                                       u16* __restrict__ fh,
                                                       u16* __restrict__ fl)
{
    int b  = blockIdx.x;
    int jg = blockIdx.y;
    __shared__ float Gs[16][256];           // [jj][m]
    int tid = threadIdx.x;
    #pragma unroll
    for (int jj = 0; jj < 16; ++jj)
        Gs[jj][tid] = G[(size_t)b * 65536 + (size_t)tid * 256 + jg * 16 + jj];
    __syncthreads();
    int i = tid;
    float acc[16];
    #pragma unroll
    for (int jj = 0; jj < 16; ++jj) acc[jj] = 0.0f;
    for (int m = 0; m < 256; ++m) {
        float wv = Wq[(size_t)i * 256 + m];
        #pragma unroll
        for (int jj = 0; jj < 16; ++jj) acc[jj] += wv * Gs[jj][m];
    }
    #pragma unroll
    for (int jj = 0; jj < 16; ++jj) {
        bfpair p = fsplit(acc[jj]);
        size_t off = (size_t)b * 65536 + (size_t)(jg * 16 + jj) * 256 + i;
        fh[off] = p.hi; fl[off] = p.lo;
    }
}

// ---------------------------------------------------------------------------
// Final: out[row] = LN(h[row]) . out_W + out_b
// ---------------------------------------------------------------------------
__global__ __launch_bounds__(256) void final_kernel(const float* __restrict__ h,
                                                    const float* __restrict__ g,
                                                    const float* __restrict__ bb,
                                                    const float* __restrict__ W,
                                                    const float* __restrict__ ob,
                                                    float* __restrict__ out)
{
    int row  = blockIdx.x * 4 + (threadIdx.x >> 6);
    int lane = threadIdx.x & 63;
    const float4 v = ((const float4*)(h + (size_t)row * H_))[lane];
    float s = v.x + v.y + v.z + v.w;
    #pragma unroll
    for (int m = 1; m < 64; m <<= 1) s += __shfl_xor(s, m, 64);
    float mean = s * (1.0f / H_);
    float dx = v.x - mean, dy = v.y - mean, dz = v.z - mean, dw = v.w - mean;
    float sq = dx * dx + dy * dy + dz * dz + dw * dw;
    #pragma unroll
    for (int m = 1; m < 64; m <<= 1) sq += __shfl_xor(sq, m, 64);
    float rstd = rsqrtf(sq * (1.0f / H_) + 1e-5f);
    float4 G = ((const float4*)g)[lane];
    float4 Bv = ((const float4*)bb)[lane];
    float4 Wv = ((const float4*)W)[lane];
    float s2 = (dx * rstd * G.x + Bv.x) * Wv.x
             + (dy * rstd * G.y + Bv.y) * Wv.y
             + (dz * rstd * G.z + Bv.z) * Wv.z
             + (dw * rstd * G.w + Bv.w) * Wv.w;
    #pragma unroll
    for (int m = 1; m < 64; m <<= 1) s2 += __shfl_xor(s2, m, 64);
    if (lane == 0) out[row] = s2 + ob[0];
}

// ---------------------------------------------------------------------------
extern "C" void kernel_launch(void* const* d_in, const int* in_sizes, int n_in,
                              void* d_out, int out_size, void* d_ws, size_t ws_size,
                              hipStream_t stream)
{
    const float* x        = (const float*)d_in[0];
    const float* pre_W1   = (const float*)d_in[1];
    const float* pre_b1   = (const float*)d_in[2];
    const float* pre_W2   = (const float*)d_in[3];
    const float* pre_b2   = (const float*)d_in[4];
    const float* placeholder = (const float*)d_in[5];
    const float* ln1_g    = (const float*)d_in[6];
    const float* ln1_b    = (const float*)d_in[7];
    const float* ln1a_g   = (const float*)d_in[8];
    const float* ln1a_b   = (const float*)d_in[9];
    const float* Wq       = (const float*)d_in[10];
    const float* Wk       = (const float*)d_in[11];
    const float* Wv       = (const float*)d_in[12];
    const float* Wo       = (const float*)d_in[13];
    const float* bo       = (const float*)d_in[14];
    const float* kn_g     = (const float*)d_in[15];
    const float* kn_b     = (const float*)d_in[16];
    const float* vn_g     = (const float*)d_in[17];
    const float* vn_b     = (const float*)d_in[18];
    const float* ln2_g    = (const float*)d_in[19];
    const float* ln2_b    = (const float*)d_in[20];
    const float* mlp_W1   = (const float*)d_in[21];
    const float* mlp_b1   = (const float*)d_in[22];
    const float* mlp_W2   = (const float*)d_in[23];
    const float* mlp_b2   = (const float*)d_in[24];
    const float* ln3_g    = (const float*)d_in[25];
    const float* ln3_b    = (const float*)d_in[26];
    const float* out_W    = (const float*)d_in[27];
    const float* out_b    = (const float*)d_in[28];

    // ---- workspace layout (~197 MB) ----
    float* ws   = (float*)d_ws;
    float* h    = ws;                       // [M,H] fp32
    float* ctxp = ws + BUF;                 // [8,64,32,32]
    float* Gbuf = ctxp + 524288;            // [8,256,256] fp32
    float* lng  = Gbuf + 524288;            // [NL,512]
    float* lnb  = lng + NL_ * 512;          // [NL,512]
    u16* ub = (u16*)(lnb + NL_ * 512);
    u16* xa_h = ub;                         // fx / xq / y (hi)
    u16* xa_l = xa_h + BUF;
    u16* xb_h = xa_l + BUF;                 // xkv; hid_h spans xb_h..xb_l
    u16* xb_l = xb_h + BUF;
    u16* kv_h = xb_l + BUF;                 // [M,512] hi; pre-hidden hi span
    u16* kv_l = kv_h + 2 * BUF;             // [M,512] lo; pre-hidden lo span
    u16* wt   = kv_l + 2 * BUF;
    u16* w_pre1h = wt;               u16* w_pre1l = w_pre1h + 49152;     // [512][96]
    u16* w_pre2h = w_pre1l + 49152;  u16* w_pre2l = w_pre2h + 131072;    // [256][512]
    u16* w_kvh = w_pre2l + 131072;   u16* w_kvl = w_kvh + 786432;        // 6x[512][256]
    u16* w_m1h = w_kvl + 786432;     u16* w_m1l = w_m1h + 1572864;       // 6x[1024][256]
    u16* w_m2h = w_m1l + 1572864;    u16* w_m2l = w_m2h + 1572864;       // 6x[256][1024]
    u16* f_h   = w_m2l + 1572864;    u16* f_l   = f_h + 524288;          // 8x[256][256]

    // ---- weight convert+transpose+split, LN-affine concat ----
    tconv_kernel<<<(512 * 96 + 255) / 256, 256, 0, stream>>>(pre_W1, w_pre1h, w_pre1l, 65, 512, 96, 1, 49152);
    tconv_kernel<<<(256 * 512 + 255) / 256, 256, 0, stream>>>(pre_W2, w_pre2h, w_pre2l, 512, 256, 512, 1, 131072);
    tconv_kernel<<<(6 * 65536 + 255) / 256, 256, 0, stream>>>(Wk, w_kvh, w_kvl, 256, 256, 256, 6, 131072);
    tconv_kernel<<<(6 * 65536 + 255) / 256, 256, 0, stream>>>(Wv, w_kvh + 65536, w_kvl + 65536, 256, 256, 256, 6, 131072);
    tconv_kernel<<<(6 * 262144 + 255) / 256, 256, 0, stream>>>(mlp_W1, w_m1h, w_m1l, 256, 1024, 256, 6, 262144);
    tconv_kernel<<<(6 * 262144 + 255) / 256, 256, 0, stream>>>(mlp_W2, w_m2h, w_m2l, 1024, 256, 1024, 6, 262144);
    lnfold_kernel<<<(NL_ * 512 + 255) / 256, 256, 0, stream>>>(kn_g, kn_b, vn_g, vn_b, lng, lnb);

    // ---- pre-stage (full M): fx -> gelu(fx@W1) -> @W2 + placeholder -> h ----
    fx_kernel<<<(M_ * 96 + 255) / 256, 256, 0, stream>>>(x, xa_h, xa_l);
    gemm_split<1, 128, 3><<<dim3(512 / 128, M_ / 128), 256, 0, stream>>>(
        xa_h, xa_l, w_pre1h, w_pre1l, nullptr, kv_h, kv_l,
        pre_b1, nullptr, nullptr, nullptr, M_, 512, 96, 0);
    gemm_split<3, 128, 3><<<dim3(256 / 128, M_ / 128), 256, 0, stream>>>(
        kv_h, kv_l, w_pre2h, w_pre2l, h, nullptr, nullptr,
        pre_b2, placeholder, nullptr, nullptr, M_, 256, 512, 0);

    for (int l = 0; l < NL_; ++l) {
        // xq -> xa pair, xkv -> xb pair
        ln_dual_kernel<<<M_ / 4, 256, 0, stream>>>(
            h, xa_h, xa_l, xb_h, xb_l, ln1_g + l * H_, ln1_b + l * H_,
            ln1a_g + l * H_, ln1a_b + l * H_);

        // fused kv = per-head-LN( xkv @ [Wk;Wv] ) -> kv pair [M,512]
        gemm_split<4, 128, 2><<<dim3(512 / 128, M_ / 128), 256, 0, stream>>>(
            xb_h, xb_l, w_kvh + (size_t)l * 131072, w_kvl + (size_t)l * 131072,
            nullptr, kv_h, kv_l, nullptr, nullptr,
            lng + l * 512, lnb + l * 512, M_, 512, H_, 0);

        // ctx partials; compose1 (fused reduce) ; compose2
        ctx_partial_kernel<<<dim3(64, 8), 256, 0, stream>>>(kv_h, kv_l, ctxp);
        compose1_kernel<<<64, 256, 0, stream>>>(ctxp, Wo + (size_t)l * 65536, Gbuf);
        compose2_kernel<<<dim3(8, 16), 256, 0, stream>>>(Wq + (size_t)l * 65536, Gbuf, f_h, f_l);

        // h += xq @ F[batch] + bo   (TERMS=2, BN=64: 1024-block grid)
        gemm_split<2, 64, 2><<<dim3(256 / 64, M_ / 128), 256, 0, stream>>>(
            xa_h, xa_l, f_h, f_l, h, nullptr, nullptr, bo + l * H_, nullptr,
            nullptr, nullptr, M_, H_, H_, 65536);

        // y -> xa pair
        ln_dual_kernel<<<M_ / 4, 256, 0, stream>>>(
            h, xa_h, xa_l, nullptr, nullptr, ln2_g + l * H_, ln2_b + l * H_, nullptr, nullptr);

        // MLP in 2 half passes; hidden [M/2,1024] pair: hi in xb span, lo in kv_h span
        for (int half = 0; half < 2; ++half) {
            size_t ao = (size_t)half * (M_ / 2) * H_;
            gemm_split<1, 128, 3><<<dim3(DFF_ / 128, (M_ / 2) / 128), 256, 0, stream>>>(
                xa_h + ao, xa_l + ao, w_m1h + (size_t)l * 262144, w_m1l + (size_t)l * 262144,
                nullptr, xb_h, kv_h, mlp_b1 + (size_t)l * DFF_, nullptr,
                nullptr, nullptr, M_ / 2, DFF_, H_, 0);
            gemm_split<2, 64, 3><<<dim3(256 / 64, (M_ / 2) / 128), 256, 0, stream>>>(
                xb_h, kv_h, w_m2h + (size_t)l * 262144, w_m2l + (size_t)l * 262144,
                h + ao, nullptr, nullptr, mlp_b2 + (size_t)l * H_, nullptr,
                nullptr, nullptr, M_ / 2, H_, DFF_, 0);
        }
    }

    final_kernel<<<M_ / 4, 256, 0, stream>>>(
        h, ln3_g, ln3_b, out_W, out_b, (float*)d_out);
}

// Round 17
// 2042.708 us; speedup vs baseline: 1.0169x; 1.0169x over previous
//
#include <hip/hip_runtime.h>
#include <cmath>

#define B_    8
#define INS_  32
#define OUTS_ 64
#define REF_  8
#define H_    256
#define NH_   8
#define DH_   32
#define NL_   6
#define DFF_  1024
#define N_    4096
#define M_    (B_*N_)      // 32768 rows
#define BUF   8388608ull   // M*H elements

typedef unsigned short u16;
typedef unsigned int   u32;
typedef __attribute__((ext_vector_type(8))) short  bf16x8;
typedef __attribute__((ext_vector_type(4))) float  f32x4;
typedef __attribute__((ext_vector_type(4))) unsigned short u16x4;

struct bfpair { u16 hi, lo; };

__device__ __forceinline__ float gelu_f(float x){
    return 0.5f * x * (1.0f + erff(x * 0.70710678118654752f));
}
__device__ __forceinline__ u16 f2b(float f){
    union { float f; u32 u; } v; v.f = f;
    u32 r = v.u + 0x7fffu + ((v.u >> 16) & 1u);
    return (u16)(r >> 16);
}
__device__ __forceinline__ float b2f(u16 b){
    union { u32 u; float f; } v; v.u = ((u32)b) << 16;
    return v.f;
}
__device__ __forceinline__ bfpair fsplit(float x){
    bfpair p;
    p.hi = f2b(x);
    p.lo = f2b(x - b2f(p.hi));
    return p;
}

// ---------------------------------------------------------------------------
// Weight convert+transpose+split: out[l*lstride + n*Kpad + k] = split(in[l][k][n])
// ---------------------------------------------------------------------------
__global__ __launch_bounds__(256) void tconv_kernel(const float* __restrict__ in,
                                                    u16* __restrict__ oh,
                                                    u16* __restrict__ ol,
                                                    int K, int N, int Kpad, int nl,
                                                    int lstride)
{
    int idx = blockIdx.x * 256 + threadIdx.x;
    int per = N * Kpad;
    if (idx >= nl * per) return;
    int l = idx / per;
    int rem = idx - l * per;
    int n = rem / Kpad;
    int k = rem - n * Kpad;
    float v = (k < K) ? in[(size_t)l * K * N + (size_t)k * N + n] : 0.0f;
    bfpair p = fsplit(v);
    size_t o = (size_t)l * lstride + (size_t)n * Kpad + k;
    oh[o] = p.hi; ol[o] = p.lo;
}

// ---------------------------------------------------------------------------
// Concatenate kn||vn affines per layer -> [NL][512] fp32
// ---------------------------------------------------------------------------
__global__ __launch_bounds__(256) void lnfold_kernel(const float* __restrict__ kg,
                                                     const float* __restrict__ kb,
                                                     const float* __restrict__ vg,
                                                     const float* __restrict__ vb,
                                                     float* __restrict__ lng,
                                                     float* __restrict__ lnb)
{
    int idx = blockIdx.x * 256 + threadIdx.x;
    if (idx >= NL_ * 512) return;
    int l = idx >> 9, c = idx & 511;
    if (c < 256) { lng[idx] = kg[l * 256 + c];       lnb[idx] = kb[l * 256 + c]; }
    else         { lng[idx] = vg[l * 256 + c - 256]; lnb[idx] = vb[l * 256 + c - 256]; }
}

// ---------------------------------------------------------------------------
// fx builder -> split bf16 [M, 128] (cols 0..64 real, rest zero; K padded for BK=64)
// ---------------------------------------------------------------------------
__global__ __launch_bounds__(256) void fx_kernel(const float* __restrict__ x,
                                                 u16* __restrict__ fh,
                                                 u16* __restrict__ fl)
{
    int idx = blockIdx.x * 256 + threadIdx.x;
    const int total = M_ * 128;
    if (idx >= total) return;
    int f   = idx & 127;
    int row = idx >> 7;
    int n   = row % N_;
    int b   = row / N_;
    int gi = n >> 6, gj = n & 63;
    float v = 0.0f;
    if (f == 0) {
        float ci = gi * (31.0f / 63.0f);
        float cj = gj * (31.0f / 63.0f);
        int i0 = (int)floorf(ci); int i1 = min(i0 + 1, 31);
        int j0 = (int)floorf(cj); int j1 = min(j0 + 1, 31);
        float wi = ci - (float)i0, wj = cj - (float)j0;
        const float* xb = x + (size_t)b * INS_ * INS_ * 3 + 2;  // channel 2
        float v00 = xb[(i0 * 32 + j0) * 3];
        float v01 = xb[(i0 * 32 + j1) * 3];
        float v10 = xb[(i1 * 32 + j0) * 3];
        float v11 = xb[(i1 * 32 + j1) * 3];
        float r0 = v00 * (1.0f - wi) + v10 * wi;
        float r1 = v01 * (1.0f - wi) + v11 * wi;
        v = r0 * (1.0f - wj) + r1 * wj;
    } else if (f < 65) {
        int r = f - 1;
        int ri = r >> 3, rj = r & 7;
        float dx = gi * (1.0f / 63.0f) - ri * (1.0f / 7.0f);
        float dy = gj * (1.0f / 63.0f) - rj * (1.0f / 7.0f);
        v = sqrtf(dx * dx + dy * dy);
    }
    bfpair p = fsplit(v);
    fh[idx] = p.hi; fl[idx] = p.lo;
}

// ---------------------------------------------------------------------------
// Split-bf16 MFMA GEMM, BK=64 single-buffer K-loop (4 steps at K=256):
// half the barrier-drains of BK=32, double the MFMA per step. Per-acc k-order
// unchanged (ascending 32-chunks) -> bit-identical to BK=32 versions.
// TERMS=3: hi*hi + lo*hi + hi*lo (~fp32).  TERMS=2: hi*hi + lo*hi.
// EPI: 0 = split store, 1 = gelu->split store, 2 = f32 +=, 3 = f32 store +b2,
//      4 = fused per-head LN (DH=32) -> split store (kv path; BN=128 only).
// bstride: elements to advance Bh/Bl per 4096 A-rows (batched B); 0 = shared.
// XCD-aware chunked block swizzle (all grids divisible by 8).
// K % 64 == 0 required.
// ---------------------------------------------------------------------------
template<int EPI, int BN, int TERMS>
__global__ __launch_bounds__(256) void gemm_split(const u16* __restrict__ Ah,
                                                  const u16* __restrict__ Al,
                                                  const u16* __restrict__ Bh,
                                                  const u16* __restrict__ Bl,
                                                  float* __restrict__ Cf,
                                                  u16* __restrict__ Ch,
                                                  u16* __restrict__ Cl,
                                                  const float* __restrict__ bias,
                                                  const float* __restrict__ bias2,
                                                  const float* __restrict__ lng,
                                                  const float* __restrict__ lnb,
                                                  int M, int Nn, int K, int bstride)
{
    constexpr int NREP = BN / 32;           // frags per wave in N
    __shared__ u16 AsH[128 * 64];
    __shared__ u16 BsH[BN * 64];
    __shared__ u16 AsL[TERMS >= 2 ? 128 * 64 : 1];
    __shared__ u16 BsL[TERMS == 3 ? BN * 64 : 1];
    const int tid = threadIdx.x;
    const int nwgx = gridDim.x;
    const int nwg  = nwgx * gridDim.y;
    const int bid  = blockIdx.y * nwgx + blockIdx.x;
    const int swz  = (bid & 7) * (nwg >> 3) + (bid >> 3);
    const int bm = (swz / nwgx) * 128;
    const int bn = (swz % nwgx) * BN;
    const u16* BhB = Bh + (size_t)(bm >> 12) * bstride;
    const u16* BlB = Bl + (size_t)(bm >> 12) * bstride;
    const int l  = tid & 63;
    const int w  = tid >> 6;
    const int wr = w >> 1, wc = w & 1;
    const int lrow = l & 15;
    const int kh   = l >> 4;       // 0..3

    auto stage = [&](int k0) {
        #pragma unroll
        for (int i = 0; i < 4; ++i) {       // A tile: 128 rows x 64 k
            int L = i * 256 + tid;
            int row = L >> 3, ch = L & 7;
            size_t goffA = (size_t)(bm + row) * K + k0 + ch * 8;
            __builtin_amdgcn_global_load_lds(
                (const __attribute__((address_space(1))) void*)(Ah + goffA),
                (__attribute__((address_space(3))) void*)(AsH + L * 8), 16, 0, 0);
            if constexpr (TERMS >= 2)
                __builtin_amdgcn_global_load_lds(
                    (const __attribute__((address_space(1))) void*)(Al + goffA),
                    (__attribute__((address_space(3))) void*)(AsL + L * 8), 16, 0, 0);
        }
        #pragma unroll
        for (int i = 0; i < BN / 32; ++i) { // B tile: BN rows x 64 k
            int L = i * 256 + tid;
            int row = L >> 3, ch = L & 7;
            size_t goffB = (size_t)(bn + row) * K + k0 + ch * 8;
            __builtin_amdgcn_global_load_lds(
                (const __attribute__((address_space(1))) void*)(BhB + goffB),
                (__attribute__((address_space(3))) void*)(BsH + L * 8), 16, 0, 0);
            if constexpr (TERMS == 3)
                __builtin_amdgcn_global_load_lds(
                    (const __attribute__((address_space(1))) void*)(BlB + goffB),
                    (__attribute__((address_space(3))) void*)(BsL + L * 8), 16, 0, 0);
        }
    };

    f32x4 acc[4][NREP];
    #pragma unroll
    for (int m = 0; m < 4; ++m)
        #pragma unroll
        for (int n = 0; n < NREP; ++n)
            acc[m][n] = (f32x4){0.0f, 0.0f, 0.0f, 0.0f};

    const int nk = K >> 6;
    for (int t = 0; t < nk; ++t) {
        stage(t << 6);
        __syncthreads();
        #pragma unroll
        for (int kk = 0; kk < 2; ++kk) {
            bf16x8 afh[4], afl[4], bfh[NREP], bfl[NREP];
            #pragma unroll
            for (int m = 0; m < 4; ++m) {
                int off = (wr * 64 + m * 16 + lrow) * 64 + kk * 32 + kh * 8;
                afh[m] = *(const bf16x8*)(AsH + off);
                if constexpr (TERMS >= 2) afl[m] = *(const bf16x8*)(AsL + off);
            }
            #pragma unroll
            for (int n = 0; n < NREP; ++n) {
                int off = (wc * (BN / 2) + n * 16 + lrow) * 64 + kk * 32 + kh * 8;
                bfh[n] = *(const bf16x8*)(BsH + off);
                if constexpr (TERMS == 3) bfl[n] = *(const bf16x8*)(BsL + off);
            }
            #pragma unroll
            for (int m = 0; m < 4; ++m)
                #pragma unroll
                for (int n = 0; n < NREP; ++n) {
                    acc[m][n] = __builtin_amdgcn_mfma_f32_16x16x32_bf16(afh[m], bfh[n], acc[m][n], 0, 0, 0);
                    if constexpr (TERMS >= 2)
                        acc[m][n] = __builtin_amdgcn_mfma_f32_16x16x32_bf16(afl[m], bfh[n], acc[m][n], 0, 0, 0);
                    if constexpr (TERMS == 3)
                        acc[m][n] = __builtin_amdgcn_mfma_f32_16x16x32_bf16(afh[m], bfl[n], acc[m][n], 0, 0, 0);
                }
        }
        if (t + 1 < nk) __syncthreads();    // release LDS for next stage
    }

    const int row0 = bm + wr * 64;
    const int col0 = bn + wc * (BN / 2);

    if constexpr (EPI == 4) {
        // fused per-head LayerNorm over DH=32 (stats via 16-lane shfl groups)
        #pragma unroll
        for (int m = 0; m < 4; ++m) {
            #pragma unroll
            for (int j = 0; j < 4; ++j) {
                int r = row0 + m * 16 + kh * 4 + j;
                #pragma unroll
                for (int hp = 0; hp < NREP / 2; ++hp) {
                    float a0 = acc[m][2 * hp + 0][j];
                    float a1 = acc[m][2 * hp + 1][j];
                    float s = a0 + a1;
                    s += __shfl_xor(s, 1); s += __shfl_xor(s, 2);
                    s += __shfl_xor(s, 4); s += __shfl_xor(s, 8);
                    float mean = s * (1.0f / 32.0f);
                    float d0 = a0 - mean, d1 = a1 - mean;
                    float q = d0 * d0 + d1 * d1;
                    q += __shfl_xor(q, 1); q += __shfl_xor(q, 2);
                    q += __shfl_xor(q, 4); q += __shfl_xor(q, 8);
                    float rstd = rsqrtf(q * (1.0f / 32.0f) + 1e-5f);
                    #pragma unroll
                    for (int t = 0; t < 2; ++t) {
                        int n = 2 * hp + t;
                        int col = col0 + n * 16 + lrow;
                        float dd = t ? d1 : d0;
                        float o = dd * rstd * lng[col] + lnb[col];
                        bfpair p = fsplit(o);
                        size_t idx = (size_t)r * Nn + col;
                        Ch[idx] = p.hi; Cl[idx] = p.lo;
                    }
                }
            }
        }
        return;
    }

    #pragma unroll
    for (int m = 0; m < 4; ++m) {
        #pragma unroll
        for (int n = 0; n < NREP; ++n) {
            int col = col0 + n * 16 + lrow;
            float bv = bias ? bias[col] : 0.0f;
            if (EPI == 3) bv += bias2[col];
            #pragma unroll
            for (int j = 0; j < 4; ++j) {
                int r = row0 + m * 16 + kh * 4 + j;
                float v = acc[m][n][j] + bv;
                size_t idx = (size_t)r * Nn + col;
                if (EPI == 0) {
                    bfpair p = fsplit(v);
                    Ch[idx] = p.hi; Cl[idx] = p.lo;
                } else if (EPI == 1) {
                    bfpair p = fsplit(gelu_f(v));
                    Ch[idx] = p.hi; Cl[idx] = p.lo;
                } else if (EPI == 2) {
                    Cf[idx] += v;
                } else {
                    Cf[idx] = v;
                }
            }
        }
    }
}

// ---------------------------------------------------------------------------
// Dual LayerNorm over H=256 (fp32 in, split bf16 out). o2h==nullptr -> single.
// ---------------------------------------------------------------------------
__global__ __launch_bounds__(256) void ln_dual_kernel(const float* __restrict__ h,
                                                      u16* __restrict__ o1h,
                                                      u16* __restrict__ o1l,
                                                      u16* __restrict__ o2h,
                                                      u16* __restrict__ o2l,
                                                      const float* __restrict__ g1,
                                                      const float* __restrict__ b1,
                                                      const float* __restrict__ g2,
                                                      const float* __restrict__ b2)
{
    int row  = blockIdx.x * 4 + (threadIdx.x >> 6);
    int lane = threadIdx.x & 63;
    const float4 v = ((const float4*)(h + (size_t)row * H_))[lane];
    float s = v.x + v.y + v.z + v.w;
    #pragma unroll
    for (int m = 1; m < 64; m <<= 1) s += __shfl_xor(s, m, 64);
    float mean = s * (1.0f / H_);
    float dx = v.x - mean, dy = v.y - mean, dz = v.z - mean, dw = v.w - mean;
    float sq = dx * dx + dy * dy + dz * dz + dw * dw;
    #pragma unroll
    for (int m = 1; m < 64; m <<= 1) sq += __shfl_xor(sq, m, 64);
    float rstd = rsqrtf(sq * (1.0f / H_) + 1e-5f);

    float4 G = ((const float4*)g1)[lane];
    float4 Bv = ((const float4*)b1)[lane];
    u16x4 oh, ol;
    bfpair p0 = fsplit(dx * rstd * G.x + Bv.x);
    bfpair p1 = fsplit(dy * rstd * G.y + Bv.y);
    bfpair p2 = fsplit(dz * rstd * G.z + Bv.z);
    bfpair p3 = fsplit(dw * rstd * G.w + Bv.w);
    oh.x = p0.hi; ol.x = p0.lo;
    oh.y = p1.hi; ol.y = p1.lo;
    oh.z = p2.hi; ol.z = p2.lo;
    oh.w = p3.hi; ol.w = p3.lo;
    ((u16x4*)(o1h + (size_t)row * H_))[lane] = oh;
    ((u16x4*)(o1l + (size_t)row * H_))[lane] = ol;
    if (o2h) {
        G = ((const float4*)g2)[lane];
        Bv = ((const float4*)b2)[lane];
        p0 = fsplit(dx * rstd * G.x + Bv.x);
        p1 = fsplit(dy * rstd * G.y + Bv.y);
        p2 = fsplit(dz * rstd * G.z + Bv.z);
        p3 = fsplit(dw * rstd * G.w + Bv.w);
        oh.x = p0.hi; ol.x = p0.lo;
        oh.y = p1.hi; ol.y = p1.lo;
        oh.z = p2.hi; ol.z = p2.lo;
        oh.w = p3.hi; ol.w = p3.lo;
        ((u16x4*)(o2h + (size_t)row * H_))[lane] = oh;
        ((u16x4*)(o2l + (size_t)row * H_))[lane] = ol;
    }
}

// ---------------------------------------------------------------------------
// ctx partials over fused kv buffer: ctxp[split][b*NH+h][32][32]
// 64-row LDS staging; per-thread row order unchanged.
// ---------------------------------------------------------------------------
__global__ __launch_bounds__(256) void ctx_partial_kernel(const u16* __restrict__ kvh,
                                                          const u16* __restrict__ kvl,
                                                          float* __restrict__ ctxp)
{
    int bh = blockIdx.x;            // 0..63
    int split = blockIdx.y;         // 0..7
    int b = bh >> 3, hd = bh & 7;
    __shared__ float kc[64][32], vc[64][32];
    int tid = threadIdx.x;
    int d  = tid >> 3;
    int e0 = (tid & 7) * 4;
    float a0 = 0, a1 = 0, a2 = 0, a3 = 0;
    int nbase = split * 512;
    for (int it = 0; it < 8; ++it) {
        #pragma unroll
        for (int i = 0; i < 8; ++i) {
            int elem = i * 256 + tid;
            int row = elem >> 5, col = elem & 31;
            size_t off = ((size_t)(b * N_ + nbase + it * 64 + row)) * 512 + hd * 32 + col;
            kc[row][col] = b2f(kvh[off]) + b2f(kvl[off]);
            vc[row][col] = b2f(kvh[off + 256]) + b2f(kvl[off + 256]);
        }
        __syncthreads();
        #pragma unroll
        for (int r = 0; r < 64; ++r) {
            float kd = kc[r][d];
            a0 += kd * vc[r][e0 + 0];
            a1 += kd * vc[r][e0 + 1];
            a2 += kd * vc[r][e0 + 2];
            a3 += kd * vc[r][e0 + 3];
        }
        __syncthreads();
    }
    float* out = ctxp + ((size_t)(split * 64 + bh)) * 1024 + d * 32 + e0;
    out[0] = a0; out[1] = a1; out[2] = a2; out[3] = a3;
}

// ---------------------------------------------------------------------------
// compose1 (fused ctx-reduce): G[b][hd*32+d][j] =
//   sum_e ( (1/N) * sum_sp ctxp[sp][b*8+hd][d][e] ) * Wo[hd*32+e][j]
// ---------------------------------------------------------------------------
__global__ __launch_bounds__(256) void compose1_kernel(const float* __restrict__ ctxp,
                                                       const float* __restrict__ Wo,
                                                       float* __restrict__ G)
{
    int b  = blockIdx.x >> 3;
    int hd = blockIdx.x & 7;
    __shared__ float cl[32][32];
    __shared__ float wl[32][256];
    int tid = threadIdx.x;
    {
        const float* src = ctxp + ((size_t)(b * 8 + hd)) * 1024;
        #pragma unroll
        for (int i = 0; i < 4; ++i) {
            float s = 0.0f;
            #pragma unroll
            for (int sp = 0; sp < 8; ++sp)
                s += src[(size_t)sp * 65536 + tid + 256 * i];
            ((float*)cl)[tid + 256 * i] = s * (1.0f / N_);
        }
        #pragma unroll
        for (int i = 0; i < 32; ++i)
            wl[i][tid] = Wo[(size_t)(hd * 32 + i) * 256 + tid];
    }
    __syncthreads();
    int j = tid;
    for (int d = 0; d < 32; ++d) {
        float s = 0.0f;
        #pragma unroll
        for (int e = 0; e < 32; ++e) s += cl[d][e] * wl[e][j];
        G[((size_t)b * 256 + hd * 32 + d) * 256 + j] = s;
    }
}

// ---------------------------------------------------------------------------
// compose2: F_t[b][j][i] = split( sum_m Wq[i][m] * G[b][m][j] )
// ---------------------------------------------------------------------------
__global__ __launch_bounds__(256) void compose2_kernel(const float* __restrict__ Wq,
                                                       const float* __restrict__ G,
                                                       u16* __restrict__ fh,
                                                       u16* __restrict__ fl)
{
    int b  = blockIdx.x;
    int jg = blockIdx.y;
    __shared__ float Gs[16][256];           // [jj][m]
    int tid = threadIdx.x;
    #pragma unroll
    for (int jj = 0; jj < 16; ++jj)
        Gs[jj][tid] = G[(size_t)b * 65536 + (size_t)tid * 256 + jg * 16 + jj];
    __syncthreads();
    int i = tid;
    float acc[16];
    #pragma unroll
    for (int jj = 0; jj < 16; ++jj) acc[jj] = 0.0f;
    for (int m = 0; m < 256; ++m) {
        float wv = Wq[(size_t)i * 256 + m];
        #pragma unroll
        for (int jj = 0; jj < 16; ++jj) acc[jj] += wv * Gs[jj][m];
    }
    #pragma unroll
    for (int jj = 0; jj < 16; ++jj) {
        bfpair p = fsplit(acc[jj]);
        size_t off = (size_t)b * 65536 + (size_t)(jg * 16 + jj) * 256 + i;
        fh[off] = p.hi; fl[off] = p.lo;
    }
}

// ---------------------------------------------------------------------------
// Final: out[row] = LN(h[row]) . out_W + out_b
// ---------------------------------------------------------------------------
__global__ __launch_bounds__(256) void final_kernel(const float* __restrict__ h,
                                                    const float* __restrict__ g,
                                                    const float* __restrict__ bb,
                                                    const float* __restrict__ W,
                                                    const float* __restrict__ ob,
                                                    float* __restrict__ out)
{
    int row  = blockIdx.x * 4 + (threadIdx.x >> 6);
    int lane = threadIdx.x & 63;
    const float4 v = ((const float4*)(h + (size_t)row * H_))[lane];
    float s = v.x + v.y + v.z + v.w;
    #pragma unroll
    for (int m = 1; m < 64; m <<= 1) s += __shfl_xor(s, m, 64);
    float mean = s * (1.0f / H_);
    float dx = v.x - mean, dy = v.y - mean, dz = v.z - mean, dw = v.w - mean;
    float sq = dx * dx + dy * dy + dz * dz + dw * dw;
    #pragma unroll
    for (int m = 1; m < 64; m <<= 1) sq += __shfl_xor(sq, m, 64);
    float rstd = rsqrtf(sq * (1.0f / H_) + 1e-5f);
    float4 G = ((const float4*)g)[lane];
    float4 Bv = ((const float4*)bb)[lane];
    float4 Wv = ((const float4*)W)[lane];
    float s2 = (dx * rstd * G.x + Bv.x) * Wv.x
             + (dy * rstd * G.y + Bv.y) * Wv.y
             + (dz * rstd * G.z + Bv.z) * Wv.z
             + (dw * rstd * G.w + Bv.w) * Wv.w;
    #pragma unroll
    for (int m = 1; m < 64; m <<= 1) s2 += __shfl_xor(s2, m, 64);
    if (lane == 0) out[row] = s2 + ob[0];
}

// ---------------------------------------------------------------------------
extern "C" void kernel_launch(void* const* d_in, const int* in_sizes, int n_in,
                              void* d_out, int out_size, void* d_ws, size_t ws_size,
                              hipStream_t stream)
{
    const float* x        = (const float*)d_in[0];
    const float* pre_W1   = (const float*)d_in[1];
    const float* pre_b1   = (const float*)d_in[2];
    const float* pre_W2   = (const float*)d_in[3];
    const float* pre_b2   = (const float*)d_in[4];
    const float* placeholder = (const float*)d_in[5];
    const float* ln1_g    = (const float*)d_in[6];
    const float* ln1_b    = (const float*)d_in[7];
    const float* ln1a_g   = (const float*)d_in[8];
    const float* ln1a_b   = (const float*)d_in[9];
    const float* Wq       = (const float*)d_in[10];
    const float* Wk       = (const float*)d_in[11];
    const float* Wv       = (const float*)d_in[12];
    const float* Wo       = (const float*)d_in[13];
    const float* bo       = (const float*)d_in[14];
    const float* kn_g     = (const float*)d_in[15];
    const float* kn_b     = (const float*)d_in[16];
    const float* vn_g     = (const float*)d_in[17];
    const float* vn_b     = (const float*)d_in[18];
    const float* ln2_g    = (const float*)d_in[19];
    const float* ln2_b    = (const float*)d_in[20];
    const float* mlp_W1   = (const float*)d_in[21];
    const float* mlp_b1   = (const float*)d_in[22];
    const float* mlp_W2   = (const float*)d_in[23];
    const float* mlp_b2   = (const float*)d_in[24];
    const float* ln3_g    = (const float*)d_in[25];
    const float* ln3_b    = (const float*)d_in[26];
    const float* out_W    = (const float*)d_in[27];
    const float* out_b    = (const float*)d_in[28];

    // ---- workspace layout (~197 MB) ----
    float* ws   = (float*)d_ws;
    float* h    = ws;                       // [M,H] fp32
    float* ctxp = ws + BUF;                 // [8,64,32,32]
    float* Gbuf = ctxp + 524288;            // [8,256,256] fp32
    float* lng  = Gbuf + 524288;            // [NL,512]
    float* lnb  = lng + NL_ * 512;          // [NL,512]
    u16* ub = (u16*)(lnb + NL_ * 512);
    u16* xa_h = ub;                         // fx(128-wide) / xq / y (hi)
    u16* xa_l = xa_h + BUF;
    u16* xb_h = xa_l + BUF;                 // xkv; hid_h spans xb_h..xb_l
    u16* xb_l = xb_h + BUF;
    u16* kv_h = xb_l + BUF;                 // [M,512] hi; pre-hidden hi span
    u16* kv_l = kv_h + 2 * BUF;             // [M,512] lo; pre-hidden lo span
    u16* wt   = kv_l + 2 * BUF;
    u16* w_pre1h = wt;               u16* w_pre1l = w_pre1h + 65536;     // [512][128]
    u16* w_pre2h = w_pre1l + 65536;  u16* w_pre2l = w_pre2h + 131072;    // [256][512]
    u16* w_kvh = w_pre2l + 131072;   u16* w_kvl = w_kvh + 786432;        // 6x[512][256]
    u16* w_m1h = w_kvl + 786432;     u16* w_m1l = w_m1h + 1572864;       // 6x[1024][256]
    u16* w_m2h = w_m1l + 1572864;    u16* w_m2l = w_m2h + 1572864;       // 6x[256][1024]
    u16* f_h   = w_m2l + 1572864;    u16* f_l   = f_h + 524288;          // 8x[256][256]

    // ---- weight convert+transpose+split, LN-affine concat ----
    tconv_kernel<<<(512 * 128 + 255) / 256, 256, 0, stream>>>(pre_W1, w_pre1h, w_pre1l, 65, 512, 128, 1, 65536);
    tconv_kernel<<<(256 * 512 + 255) / 256, 256, 0, stream>>>(pre_W2, w_pre2h, w_pre2l, 512, 256, 512, 1, 131072);
    tconv_kernel<<<(6 * 65536 + 255) / 256, 256, 0, stream>>>(Wk, w_kvh, w_kvl, 256, 256, 256, 6, 131072);
    tconv_kernel<<<(6 * 65536 + 255) / 256, 256, 0, stream>>>(Wv, w_kvh + 65536, w_kvl + 65536, 256, 256, 256, 6, 131072);
    tconv_kernel<<<(6 * 262144 + 255) / 256, 256, 0, stream>>>(mlp_W1, w_m1h, w_m1l, 256, 1024, 256, 6, 262144);
    tconv_kernel<<<(6 * 262144 + 255) / 256, 256, 0, stream>>>(mlp_W2, w_m2h, w_m2l, 1024, 256, 1024, 6, 262144);
    lnfold_kernel<<<(NL_ * 512 + 255) / 256, 256, 0, stream>>>(kn_g, kn_b, vn_g, vn_b, lng, lnb);

    // ---- pre-stage (full M): fx -> gelu(fx@W1) -> @W2 + placeholder -> h ----
    fx_kernel<<<(M_ * 128 + 255) / 256, 256, 0, stream>>>(x, xa_h, xa_l);
    gemm_split<1, 128, 3><<<dim3(512 / 128, M_ / 128), 256, 0, stream>>>(
        xa_h, xa_l, w_pre1h, w_pre1l, nullptr, kv_h, kv_l,
        pre_b1, nullptr, nullptr, nullptr, M_, 512, 128, 0);
    gemm_split<3, 128, 3><<<dim3(256 / 128, M_ / 128), 256, 0, stream>>>(
        kv_h, kv_l, w_pre2h, w_pre2l, h, nullptr, nullptr,
        pre_b2, placeholder, nullptr, nullptr, M_, 256, 512, 0);

    for (int l = 0; l < NL_; ++l) {
        // xq -> xa pair, xkv -> xb pair
        ln_dual_kernel<<<M_ / 4, 256, 0, stream>>>(
            h, xa_h, xa_l, xb_h, xb_l, ln1_g + l * H_, ln1_b + l * H_,
            ln1a_g + l * H_, ln1a_b + l * H_);

        // fused kv = per-head-LN( xkv @ [Wk;Wv] ) -> kv pair [M,512]
        gemm_split<4, 128, 2><<<dim3(512 / 128, M_ / 128), 256, 0, stream>>>(
            xb_h, xb_l, w_kvh + (size_t)l * 131072, w_kvl + (size_t)l * 131072,
            nullptr, kv_h, kv_l, nullptr, nullptr,
            lng + l * 512, lnb + l * 512, M_, 512, H_, 0);

        // ctx partials; compose1 (fused reduce) ; compose2
        ctx_partial_kernel<<<dim3(64, 8), 256, 0, stream>>>(kv_h, kv_l, ctxp);
        compose1_kernel<<<64, 256, 0, stream>>>(ctxp, Wo + (size_t)l * 65536, Gbuf);
        compose2_kernel<<<dim3(8, 16), 256, 0, stream>>>(Wq + (size_t)l * 65536, Gbuf, f_h, f_l);

        // h += xq @ F[batch] + bo   (TERMS=2, BN=64: 1024-block grid)
        gemm_split<2, 64, 2><<<dim3(256 / 64, M_ / 128), 256, 0, stream>>>(
            xa_h, xa_l, f_h, f_l, h, nullptr, nullptr, bo + l * H_, nullptr,
            nullptr, nullptr, M_, H_, H_, 65536);

        // y -> xa pair
        ln_dual_kernel<<<M_ / 4, 256, 0, stream>>>(
            h, xa_h, xa_l, nullptr, nullptr, ln2_g + l * H_, ln2_b + l * H_, nullptr, nullptr);

        // MLP in 2 half passes; hidden [M/2,1024] pair: hi in xb span, lo in kv_h span
        for (int half = 0; half < 2; ++half) {
            size_t ao = (size_t)half * (M_ / 2) * H_;
            gemm_split<1, 128, 3><<<dim3(DFF_ / 128, (M_ / 2) / 128), 256, 0, stream>>>(
                xa_h + ao, xa_l + ao, w_m1h + (size_t)l * 262144, w_m1l + (size_t)l * 262144,
                nullptr, xb_h, kv_h, mlp_b1 + (size_t)l * DFF_, nullptr,
                nullptr, nullptr, M_ / 2, DFF_, H_, 0);
            gemm_split<2, 64, 3><<<dim3(256 / 64, (M_ / 2) / 128), 256, 0, stream>>>(
                xb_h, kv_h, w_m2h + (size_t)l * 262144, w_m2l + (size_t)l * 262144,
                h + ao, nullptr, nullptr, mlp_b2 + (size_t)l * H_, nullptr,
                nullptr, nullptr, M_ / 2, H_, DFF_, 0);
        }
    }

    final_kernel<<<M_ / 4, 256, 0, stream>>>(
        h, ln3_g, ln3_b, out_W, out_b, (float*)d_out);
}

// Round 18
// 1998.545 us; speedup vs baseline: 1.0394x; 1.0221x over previous
//
#include <hip/hip_runtime.h>
#include <cmath>

#define B_    8
#define INS_  32
#define OUTS_ 64
#define REF_  8
#define H_    256
#define NH_   8
#define DH_   32
#define NL_   6
#define DFF_  1024
#define N_    4096
#define M_    (B_*N_)      // 32768 rows
#define BUF   8388608ull   // M*H elements

typedef unsigned short u16;
typedef unsigned int   u32;
typedef __attribute__((ext_vector_type(8))) short  bf16x8;
typedef __attribute__((ext_vector_type(4))) float  f32x4;
typedef __attribute__((ext_vector_type(4))) unsigned short u16x4;

struct bfpair { u16 hi, lo; };

__device__ __forceinline__ float gelu_f(float x){
    return 0.5f * x * (1.0f + erff(x * 0.70710678118654752f));
}
__device__ __forceinline__ u16 f2b(float f){
    union { float f; u32 u; } v; v.f = f;
    u32 r = v.u + 0x7fffu + ((v.u >> 16) & 1u);
    return (u16)(r >> 16);
}
__device__ __forceinline__ float b2f(u16 b){
    union { u32 u; float f; } v; v.u = ((u32)b) << 16;
    return v.f;
}
__device__ __forceinline__ bfpair fsplit(float x){
    bfpair p;
    p.hi = f2b(x);
    p.lo = f2b(x - b2f(p.hi));
    return p;
}

// ---------------------------------------------------------------------------
// Weight convert+transpose+split: out[l*lstride + n*Kpad + k] = split(in[l][k][n])
// ---------------------------------------------------------------------------
__global__ __launch_bounds__(256) void tconv_kernel(const float* __restrict__ in,
                                                    u16* __restrict__ oh,
                                                    u16* __restrict__ ol,
                                                    int K, int N, int Kpad, int nl,
                                                    int lstride)
{
    int idx = blockIdx.x * 256 + threadIdx.x;
    int per = N * Kpad;
    if (idx >= nl * per) return;
    int l = idx / per;
    int rem = idx - l * per;
    int n = rem / Kpad;
    int k = rem - n * Kpad;
    float v = (k < K) ? in[(size_t)l * K * N + (size_t)k * N + n] : 0.0f;
    bfpair p = fsplit(v);
    size_t o = (size_t)l * lstride + (size_t)n * Kpad + k;
    oh[o] = p.hi; ol[o] = p.lo;
}

// ---------------------------------------------------------------------------
// Concatenate kn||vn affines per layer -> [NL][512] fp32
// ---------------------------------------------------------------------------
__global__ __launch_bounds__(256) void lnfold_kernel(const float* __restrict__ kg,
                                                     const float* __restrict__ kb,
                                                     const float* __restrict__ vg,
                                                     const float* __restrict__ vb,
                                                     float* __restrict__ lng,
                                                     float* __restrict__ lnb)
{
    int idx = blockIdx.x * 256 + threadIdx.x;
    if (idx >= NL_ * 512) return;
    int l = idx >> 9, c = idx & 511;
    if (c < 256) { lng[idx] = kg[l * 256 + c];       lnb[idx] = kb[l * 256 + c]; }
    else         { lng[idx] = vg[l * 256 + c - 256]; lnb[idx] = vb[l * 256 + c - 256]; }
}

// ---------------------------------------------------------------------------
// fx builder -> split bf16 [M, 128] (cols 0..64 real, rest zero; K padded for BK=64)
// ---------------------------------------------------------------------------
__global__ __launch_bounds__(256) void fx_kernel(const float* __restrict__ x,
                                                 u16* __restrict__ fh,
                                                 u16* __restrict__ fl)
{
    int idx = blockIdx.x * 256 + threadIdx.x;
    const int total = M_ * 128;
    if (idx >= total) return;
    int f   = idx & 127;
    int row = idx >> 7;
    int n   = row % N_;
    int b   = row / N_;
    int gi = n >> 6, gj = n & 63;
    float v = 0.0f;
    if (f == 0) {
        float ci = gi * (31.0f / 63.0f);
        float cj = gj * (31.0f / 63.0f);
        int i0 = (int)floorf(ci); int i1 = min(i0 + 1, 31);
        int j0 = (int)floorf(cj); int j1 = min(j0 + 1, 31);
        float wi = ci - (float)i0, wj = cj - (float)j0;
        const float* xb = x + (size_t)b * INS_ * INS_ * 3 + 2;  // channel 2
        float v00 = xb[(i0 * 32 + j0) * 3];
        float v01 = xb[(i0 * 32 + j1) * 3];
        float v10 = xb[(i1 * 32 + j0) * 3];
        float v11 = xb[(i1 * 32 + j1) * 3];
        float r0 = v00 * (1.0f - wi) + v10 * wi;
        float r1 = v01 * (1.0f - wi) + v11 * wi;
        v = r0 * (1.0f - wj) + r1 * wj;
    } else if (f < 65) {
        int r = f - 1;
        int ri = r >> 3, rj = r & 7;
        float dx = gi * (1.0f / 63.0f) - ri * (1.0f / 7.0f);
        float dy = gj * (1.0f / 63.0f) - rj * (1.0f / 7.0f);
        v = sqrtf(dx * dx + dy * dy);
    }
    bfpair p = fsplit(v);
    fh[idx] = p.hi; fl[idx] = p.lo;
}

// ---------------------------------------------------------------------------
// Split-bf16 MFMA GEMM, BK=64 single-buffer K-loop + XOR bank swizzle:
// LDS written linearly by global_load_lds, but each thread's GLOBAL source
// column is pre-swizzled (ch ^= row&7, 16B granules); reads apply the same
// XOR -> identical data to MFMA (bit-identical), 16-way conflict -> 2-way.
// TERMS=3: hi*hi + lo*hi + hi*lo (~fp32).  TERMS=2: hi*hi + lo*hi.
// EPI: 0 = split store, 1 = gelu->split store, 2 = f32 +=, 3 = f32 store +b2,
//      4 = fused per-head LN (DH=32) -> split store (kv path; BN=128 only).
// bstride: elements to advance Bh/Bl per 4096 A-rows (batched B); 0 = shared.
// XCD-aware chunked block swizzle (all grids divisible by 8). K % 64 == 0.
// ---------------------------------------------------------------------------
template<int EPI, int BN, int TERMS>
__global__ __launch_bounds__(256) void gemm_split(const u16* __restrict__ Ah,
                                                  const u16* __restrict__ Al,
                                                  const u16* __restrict__ Bh,
                                                  const u16* __restrict__ Bl,
                                                  float* __restrict__ Cf,
                                                  u16* __restrict__ Ch,
                                                  u16* __restrict__ Cl,
                                                  const float* __restrict__ bias,
                                                  const float* __restrict__ bias2,
                                                  const float* __restrict__ lng,
                                                  const float* __restrict__ lnb,
                                                  int M, int Nn, int K, int bstride)
{
    constexpr int NREP = BN / 32;           // frags per wave in N
    __shared__ u16 AsH[128 * 64];
    __shared__ u16 BsH[BN * 64];
    __shared__ u16 AsL[TERMS >= 2 ? 128 * 64 : 1];
    __shared__ u16 BsL[TERMS == 3 ? BN * 64 : 1];
    const int tid = threadIdx.x;
    const int nwgx = gridDim.x;
    const int nwg  = nwgx * gridDim.y;
    const int bid  = blockIdx.y * nwgx + blockIdx.x;
    const int swz  = (bid & 7) * (nwg >> 3) + (bid >> 3);
    const int bm = (swz / nwgx) * 128;
    const int bn = (swz % nwgx) * BN;
    const u16* BhB = Bh + (size_t)(bm >> 12) * bstride;
    const u16* BlB = Bl + (size_t)(bm >> 12) * bstride;
    const int l  = tid & 63;
    const int w  = tid >> 6;
    const int wr = w >> 1, wc = w & 1;
    const int lrow = l & 15;
    const int kh   = l >> 4;       // 0..3
    const int rx   = lrow & 7;     // fragment-row swizzle key

    auto stage = [&](int k0) {
        #pragma unroll
        for (int i = 0; i < 4; ++i) {       // A tile: 128 rows x 64 k
            int L = i * 256 + tid;
            int row = L >> 3, ch = L & 7;
            int chs = ch ^ (row & 7);       // pre-swizzled source column
            size_t goffA = (size_t)(bm + row) * K + k0 + chs * 8;
            __builtin_amdgcn_global_load_lds(
                (const __attribute__((address_space(1))) void*)(Ah + goffA),
                (__attribute__((address_space(3))) void*)(AsH + L * 8), 16, 0, 0);
            if constexpr (TERMS >= 2)
                __builtin_amdgcn_global_load_lds(
                    (const __attribute__((address_space(1))) void*)(Al + goffA),
                    (__attribute__((address_space(3))) void*)(AsL + L * 8), 16, 0, 0);
        }
        #pragma unroll
        for (int i = 0; i < BN / 32; ++i) { // B tile: BN rows x 64 k
            int L = i * 256 + tid;
            int row = L >> 3, ch = L & 7;
            int chs = ch ^ (row & 7);
            size_t goffB = (size_t)(bn + row) * K + k0 + chs * 8;
            __builtin_amdgcn_global_load_lds(
                (const __attribute__((address_space(1))) void*)(BhB + goffB),
                (__attribute__((address_space(3))) void*)(BsH + L * 8), 16, 0, 0);
            if constexpr (TERMS == 3)
                __builtin_amdgcn_global_load_lds(
                    (const __attribute__((address_space(1))) void*)(BlB + goffB),
                    (__attribute__((address_space(3))) void*)(BsL + L * 8), 16, 0, 0);
        }
    };

    f32x4 acc[4][NREP];
    #pragma unroll
    for (int m = 0; m < 4; ++m)
        #pragma unroll
        for (int n = 0; n < NREP; ++n)
            acc[m][n] = (f32x4){0.0f, 0.0f, 0.0f, 0.0f};

    const int nk = K >> 6;
    for (int t = 0; t < nk; ++t) {
        stage(t << 6);
        __syncthreads();
        #pragma unroll
        for (int kk = 0; kk < 2; ++kk) {
            const int csw = (kk * 4 + kh) ^ rx;     // swizzled read slot
            bf16x8 afh[4], afl[4], bfh[NREP], bfl[NREP];
            #pragma unroll
            for (int m = 0; m < 4; ++m) {
                int off = (wr * 64 + m * 16 + lrow) * 64 + csw * 8;
                afh[m] = *(const bf16x8*)(AsH + off);
                if constexpr (TERMS >= 2) afl[m] = *(const bf16x8*)(AsL + off);
            }
            #pragma unroll
            for (int n = 0; n < NREP; ++n) {
                int off = (wc * (BN / 2) + n * 16 + lrow) * 64 + csw * 8;
                bfh[n] = *(const bf16x8*)(BsH + off);
                if constexpr (TERMS == 3) bfl[n] = *(const bf16x8*)(BsL + off);
            }
            #pragma unroll
            for (int m = 0; m < 4; ++m)
                #pragma unroll
                for (int n = 0; n < NREP; ++n) {
                    acc[m][n] = __builtin_amdgcn_mfma_f32_16x16x32_bf16(afh[m], bfh[n], acc[m][n], 0, 0, 0);
                    if constexpr (TERMS >= 2)
                        acc[m][n] = __builtin_amdgcn_mfma_f32_16x16x32_bf16(afl[m], bfh[n], acc[m][n], 0, 0, 0);
                    if constexpr (TERMS == 3)
                        acc[m][n] = __builtin_amdgcn_mfma_f32_16x16x32_bf16(afh[m], bfl[n], acc[m][n], 0, 0, 0);
                }
        }
        if (t + 1 < nk) __syncthreads();    // release LDS for next stage
    }

    const int row0 = bm + wr * 64;
    const int col0 = bn + wc * (BN / 2);

    if constexpr (EPI == 4) {
        // fused per-head LayerNorm over DH=32 (stats via 16-lane shfl groups)
        #pragma unroll
        for (int m = 0; m < 4; ++m) {
            #pragma unroll
            for (int j = 0; j < 4; ++j) {
                int r = row0 + m * 16 + kh * 4 + j;
                #pragma unroll
                for (int hp = 0; hp < NREP / 2; ++hp) {
                    float a0 = acc[m][2 * hp + 0][j];
                    float a1 = acc[m][2 * hp + 1][j];
                    float s = a0 + a1;
                    s += __shfl_xor(s, 1); s += __shfl_xor(s, 2);
                    s += __shfl_xor(s, 4); s += __shfl_xor(s, 8);
                    float mean = s * (1.0f / 32.0f);
                    float d0 = a0 - mean, d1 = a1 - mean;
                    float q = d0 * d0 + d1 * d1;
                    q += __shfl_xor(q, 1); q += __shfl_xor(q, 2);
                    q += __shfl_xor(q, 4); q += __shfl_xor(q, 8);
                    float rstd = rsqrtf(q * (1.0f / 32.0f) + 1e-5f);
                    #pragma unroll
                    for (int t = 0; t < 2; ++t) {
                        int n = 2 * hp + t;
                        int col = col0 + n * 16 + lrow;
                        float dd = t ? d1 : d0;
                        float o = dd * rstd * lng[col] + lnb[col];
                        bfpair p = fsplit(o);
                        size_t idx = (size_t)r * Nn + col;
                        Ch[idx] = p.hi; Cl[idx] = p.lo;
                    }
                }
            }
        }
        return;
    }

    #pragma unroll
    for (int m = 0; m < 4; ++m) {
        #pragma unroll
        for (int n = 0; n < NREP; ++n) {
            int col = col0 + n * 16 + lrow;
            float bv = bias ? bias[col] : 0.0f;
            if (EPI == 3) bv += bias2[col];
            #pragma unroll
            for (int j = 0; j < 4; ++j) {
                int r = row0 + m * 16 + kh * 4 + j;
                float v = acc[m][n][j] + bv;
                size_t idx = (size_t)r * Nn + col;
                if (EPI == 0) {
                    bfpair p = fsplit(v);
                    Ch[idx] = p.hi; Cl[idx] = p.lo;
                } else if (EPI == 1) {
                    bfpair p = fsplit(gelu_f(v));
                    Ch[idx] = p.hi; Cl[idx] = p.lo;
                } else if (EPI == 2) {
                    Cf[idx] += v;
                } else {
                    Cf[idx] = v;
                }
            }
        }
    }
}

// ---------------------------------------------------------------------------
// Dual LayerNorm over H=256 (fp32 in, split bf16 out). o2h==nullptr -> single.
// ---------------------------------------------------------------------------
__global__ __launch_bounds__(256) void ln_dual_kernel(const float* __restrict__ h,
                                                      u16* __restrict__ o1h,
                                                      u16* __restrict__ o1l,
                                                      u16* __restrict__ o2h,
                                                      u16* __restrict__ o2l,
                                                      const float* __restrict__ g1,
                                                      const float* __restrict__ b1,
                                                      const float* __restrict__ g2,
                                                      const float* __restrict__ b2)
{
    int row  = blockIdx.x * 4 + (threadIdx.x >> 6);
    int lane = threadIdx.x & 63;
    const float4 v = ((const float4*)(h + (size_t)row * H_))[lane];
    float s = v.x + v.y + v.z + v.w;
    #pragma unroll
    for (int m = 1; m < 64; m <<= 1) s += __shfl_xor(s, m, 64);
    float mean = s * (1.0f / H_);
    float dx = v.x - mean, dy = v.y - mean, dz = v.z - mean, dw = v.w - mean;
    float sq = dx * dx + dy * dy + dz * dz + dw * dw;
    #pragma unroll
    for (int m = 1; m < 64; m <<= 1) sq += __shfl_xor(sq, m, 64);
    float rstd = rsqrtf(sq * (1.0f / H_) + 1e-5f);

    float4 G = ((const float4*)g1)[lane];
    float4 Bv = ((const float4*)b1)[lane];
    u16x4 oh, ol;
    bfpair p0 = fsplit(dx * rstd * G.x + Bv.x);
    bfpair p1 = fsplit(dy * rstd * G.y + Bv.y);
    bfpair p2 = fsplit(dz * rstd * G.z + Bv.z);
    bfpair p3 = fsplit(dw * rstd * G.w + Bv.w);
    oh.x = p0.hi; ol.x = p0.lo;
    oh.y = p1.hi; ol.y = p1.lo;
    oh.z = p2.hi; ol.z = p2.lo;
    oh.w = p3.hi; ol.w = p3.lo;
    ((u16x4*)(o1h + (size_t)row * H_))[lane] = oh;
    ((u16x4*)(o1l + (size_t)row * H_))[lane] = ol;
    if (o2h) {
        G = ((const float4*)g2)[lane];
        Bv = ((const float4*)b2)[lane];
        p0 = fsplit(dx * rstd * G.x + Bv.x);
        p1 = fsplit(dy * rstd * G.y + Bv.y);
        p2 = fsplit(dz * rstd * G.z + Bv.z);
        p3 = fsplit(dw * rstd * G.w + Bv.w);
        oh.x = p0.hi; ol.x = p0.lo;
        oh.y = p1.hi; ol.y = p1.lo;
        oh.z = p2.hi; ol.z = p2.lo;
        oh.w = p3.hi; ol.w = p3.lo;
        ((u16x4*)(o2h + (size_t)row * H_))[lane] = oh;
        ((u16x4*)(o2l + (size_t)row * H_))[lane] = ol;
    }
}

// ---------------------------------------------------------------------------
// ctx partials over fused kv buffer: ctxp[split][b*NH+h][32][32]
// 64-row LDS staging; per-thread row order unchanged.
// ---------------------------------------------------------------------------
__global__ __launch_bounds__(256) void ctx_partial_kernel(const u16* __restrict__ kvh,
                                                          const u16* __restrict__ kvl,
                                                          float* __restrict__ ctxp)
{
    int bh = blockIdx.x;            // 0..63
    int split = blockIdx.y;         // 0..7
    int b = bh >> 3, hd = bh & 7;
    __shared__ float kc[64][32], vc[64][32];
    int tid = threadIdx.x;
    int d  = tid >> 3;
    int e0 = (tid & 7) * 4;
    float a0 = 0, a1 = 0, a2 = 0, a3 = 0;
    int nbase = split * 512;
    for (int it = 0; it < 8; ++it) {
        #pragma unroll
        for (int i = 0; i < 8; ++i) {
            int elem = i * 256 + tid;
            int row = elem >> 5, col = elem & 31;
            size_t off = ((size_t)(b * N_ + nbase + it * 64 + row)) * 512 + hd * 32 + col;
            kc[row][col] = b2f(kvh[off]) + b2f(kvl[off]);
            vc[row][col] = b2f(kvh[off + 256]) + b2f(kvl[off + 256]);
        }
        __syncthreads();
        #pragma unroll
        for (int r = 0; r < 64; ++r) {
            float kd = kc[r][d];
            a0 += kd * vc[r][e0 + 0];
            a1 += kd * vc[r][e0 + 1];
            a2 += kd * vc[r][e0 + 2];
            a3 += kd * vc[r][e0 + 3];
        }
        __syncthreads();
    }
    float* out = ctxp + ((size_t)(split * 64 + bh)) * 1024 + d * 32 + e0;
    out[0] = a0; out[1] = a1; out[2] = a2; out[3] = a3;
}

// ---------------------------------------------------------------------------
// compose1 (fused ctx-reduce): G[b][hd*32+d][j] =
//   sum_e ( (1/N) * sum_sp ctxp[sp][b*8+hd][d][e] ) * Wo[hd*32+e][j]
// ---------------------------------------------------------------------------
__global__ __launch_bounds__(256) void compose1_kernel(const float* __restrict__ ctxp,
                                                       const float* __restrict__ Wo,
                                                       float* __restrict__ G)
{
    int b  = blockIdx.x >> 3;
    int hd = blockIdx.x & 7;
    __shared__ float cl[32][32];
    __shared__ float wl[32][256];
    int tid = threadIdx.x;
    {
        const float* src = ctxp + ((size_t)(b * 8 + hd)) * 1024;
        #pragma unroll
        for (int i = 0; i < 4; ++i) {
            float s = 0.0f;
            #pragma unroll
            for (int sp = 0; sp < 8; ++sp)
                s += src[(size_t)sp * 65536 + tid + 256 * i];
            ((float*)cl)[tid + 256 * i] = s * (1.0f / N_);
        }
        #pragma unroll
        for (int i = 0; i < 32; ++i)
            wl[i][tid] = Wo[(size_t)(hd * 32 + i) * 256 + tid];
    }
    __syncthreads();
    int j = tid;
    for (int d = 0; d < 32; ++d) {
        float s = 0.0f;
        #pragma unroll
        for (int e = 0; e < 32; ++e) s += cl[d][e] * wl[e][j];
        G[((size_t)b * 256 + hd * 32 + d) * 256 + j] = s;
    }
}

// ---------------------------------------------------------------------------
// compose2: F_t[b][j][i] = split( sum_m Wq[i][m] * G[b][m][j] )
// ---------------------------------------------------------------------------
__global__ __launch_bounds__(256) void compose2_kernel(const float* __restrict__ Wq,
                                                       const float* __restrict__ G,
                                                       u16* __restrict__ fh,
                                                       u16* __restrict__ fl)
{
    int b  = blockIdx.x;
    int jg = blockIdx.y;
    __shared__ float Gs[16][256];           // [jj][m]
    int tid = threadIdx.x;
    #pragma unroll
    for (int jj = 0; jj < 16; ++jj)
        Gs[jj][tid] = G[(size_t)b * 65536 + (size_t)tid * 256 + jg * 16 + jj];
    __syncthreads();
    int i = tid;
    float acc[16];
    #pragma unroll
    for (int jj = 0; jj < 16; ++jj) acc[jj] = 0.0f;
    for (int m = 0; m < 256; ++m) {
        float wv = Wq[(size_t)i * 256 + m];
        #pragma unroll
        for (int jj = 0; jj < 16; ++jj) acc[jj] += wv * Gs[jj][m];
    }
    #pragma unroll
    for (int jj = 0; jj < 16; ++jj) {
        bfpair p = fsplit(acc[jj]);
        size_t off = (size_t)b * 65536 + (size_t)(jg * 16 + jj) * 256 + i;
        fh[off] = p.hi; fl[off] = p.lo;
    }
}

// ---------------------------------------------------------------------------
// Final: out[row] = LN(h[row]) . out_W + out_b
// ---------------------------------------------------------------------------
__global__ __launch_bounds__(256) void final_kernel(const float* __restrict__ h,
                                                    const float* __restrict__ g,
                                                    const float* __restrict__ bb,
                                                    const float* __restrict__ W,
                                                    const float* __restrict__ ob,
                                                    float* __restrict__ out)
{
    int row  = blockIdx.x * 4 + (threadIdx.x >> 6);
    int lane = threadIdx.x & 63;
    const float4 v = ((const float4*)(h + (size_t)row * H_))[lane];
    float s = v.x + v.y + v.z + v.w;
    #pragma unroll
    for (int m = 1; m < 64; m <<= 1) s += __shfl_xor(s, m, 64);
    float mean = s * (1.0f / H_);
    float dx = v.x - mean, dy = v.y - mean, dz = v.z - mean, dw = v.w - mean;
    float sq = dx * dx + dy * dy + dz * dz + dw * dw;
    #pragma unroll
    for (int m = 1; m < 64; m <<= 1) sq += __shfl_xor(sq, m, 64);
    float rstd = rsqrtf(sq * (1.0f / H_) + 1e-5f);
    float4 G = ((const float4*)g)[lane];
    float4 Bv = ((const float4*)bb)[lane];
    float4 Wv = ((const float4*)W)[lane];
    float s2 = (dx * rstd * G.x + Bv.x) * Wv.x
             + (dy * rstd * G.y + Bv.y) * Wv.y
             + (dz * rstd * G.z + Bv.z) * Wv.z
             + (dw * rstd * G.w + Bv.w) * Wv.w;
    #pragma unroll
    for (int m = 1; m < 64; m <<= 1) s2 += __shfl_xor(s2, m, 64);
    if (lane == 0) out[row] = s2 + ob[0];
}

// ---------------------------------------------------------------------------
extern "C" void kernel_launch(void* const* d_in, const int* in_sizes, int n_in,
                              void* d_out, int out_size, void* d_ws, size_t ws_size,
                              hipStream_t stream)
{
    const float* x        = (const float*)d_in[0];
    const float* pre_W1   = (const float*)d_in[1];
    const float* pre_b1   = (const float*)d_in[2];
    const float* pre_W2   = (const float*)d_in[3];
    const float* pre_b2   = (const float*)d_in[4];
    const float* placeholder = (const float*)d_in[5];
    const float* ln1_g    = (const float*)d_in[6];
    const float* ln1_b    = (const float*)d_in[7];
    const float* ln1a_g   = (const float*)d_in[8];
    const float* ln1a_b   = (const float*)d_in[9];
    const float* Wq       = (const float*)d_in[10];
    const float* Wk       = (const float*)d_in[11];
    const float* Wv       = (const float*)d_in[12];
    const float* Wo       = (const float*)d_in[13];
    const float* bo       = (const float*)d_in[14];
    const float* kn_g     = (const float*)d_in[15];
    const float* kn_b     = (const float*)d_in[16];
    const float* vn_g     = (const float*)d_in[17];
    const float* vn_b     = (const float*)d_in[18];
    const float* ln2_g    = (const float*)d_in[19];
    const float* ln2_b    = (const float*)d_in[20];
    const float* mlp_W1   = (const float*)d_in[21];
    const float* mlp_b1   = (const float*)d_in[22];
    const float* mlp_W2   = (const float*)d_in[23];
    const float* mlp_b2   = (const float*)d_in[24];
    const float* ln3_g    = (const float*)d_in[25];
    const float* ln3_b    = (const float*)d_in[26];
    const float* out_W    = (const float*)d_in[27];
    const float* out_b    = (const float*)d_in[28];

    // ---- workspace layout (~197 MB) ----
    float* ws   = (float*)d_ws;
    float* h    = ws;                       // [M,H] fp32
    float* ctxp = ws + BUF;                 // [8,64,32,32]
    float* Gbuf = ctxp + 524288;            // [8,256,256] fp32
    float* lng  = Gbuf + 524288;            // [NL,512]
    float* lnb  = lng + NL_ * 512;          // [NL,512]
    u16* ub = (u16*)(lnb + NL_ * 512);
    u16* xa_h = ub;                         // fx(128-wide) / xq / y (hi)
    u16* xa_l = xa_h + BUF;
    u16* xb_h = xa_l + BUF;                 // xkv; hid_h spans xb_h..xb_l
    u16* xb_l = xb_h + BUF;
    u16* kv_h = xb_l + BUF;                 // [M,512] hi; pre-hidden hi span
    u16* kv_l = kv_h + 2 * BUF;             // [M,512] lo; pre-hidden lo span
    u16* wt   = kv_l + 2 * BUF;
    u16* w_pre1h = wt;               u16* w_pre1l = w_pre1h + 65536;     // [512][128]
    u16* w_pre2h = w_pre1l + 65536;  u16* w_pre2l = w_pre2h + 131072;    // [256][512]
    u16* w_kvh = w_pre2l + 131072;   u16* w_kvl = w_kvh + 786432;        // 6x[512][256]
    u16* w_m1h = w_kvl + 786432;     u16* w_m1l = w_m1h + 1572864;       // 6x[1024][256]
    u16* w_m2h = w_m1l + 1572864;    u16* w_m2l = w_m2h + 1572864;       // 6x[256][1024]
    u16* f_h   = w_m2l + 1572864;    u16* f_l   = f_h + 524288;          // 8x[256][256]

    // ---- weight convert+transpose+split, LN-affine concat ----
    tconv_kernel<<<(512 * 128 + 255) / 256, 256, 0, stream>>>(pre_W1, w_pre1h, w_pre1l, 65, 512, 128, 1, 65536);
    tconv_kernel<<<(256 * 512 + 255) / 256, 256, 0, stream>>>(pre_W2, w_pre2h, w_pre2l, 512, 256, 512, 1, 131072);
    tconv_kernel<<<(6 * 65536 + 255) / 256, 256, 0, stream>>>(Wk, w_kvh, w_kvl, 256, 256, 256, 6, 131072);
    tconv_kernel<<<(6 * 65536 + 255) / 256, 256, 0, stream>>>(Wv, w_kvh + 65536, w_kvl + 65536, 256, 256, 256, 6, 131072);
    tconv_kernel<<<(6 * 262144 + 255) / 256, 256, 0, stream>>>(mlp_W1, w_m1h, w_m1l, 256, 1024, 256, 6, 262144);
    tconv_kernel<<<(6 * 262144 + 255) / 256, 256, 0, stream>>>(mlp_W2, w_m2h, w_m2l, 1024, 256, 1024, 6, 262144);
    lnfold_kernel<<<(NL_ * 512 + 255) / 256, 256, 0, stream>>>(kn_g, kn_b, vn_g, vn_b, lng, lnb);

    // ---- pre-stage (full M): fx -> gelu(fx@W1) -> @W2 + placeholder -> h ----
    fx_kernel<<<(M_ * 128 + 255) / 256, 256, 0, stream>>>(x, xa_h, xa_l);
    gemm_split<1, 128, 3><<<dim3(512 / 128, M_ / 128), 256, 0, stream>>>(
        xa_h, xa_l, w_pre1h, w_pre1l, nullptr, kv_h, kv_l,
        pre_b1, nullptr, nullptr, nullptr, M_, 512, 128, 0);
    gemm_split<3, 128, 3><<<dim3(256 / 128, M_ / 128), 256, 0, stream>>>(
        kv_h, kv_l, w_pre2h, w_pre2l, h, nullptr, nullptr,
        pre_b2, placeholder, nullptr, nullptr, M_, 256, 512, 0);

    for (int l = 0; l < NL_; ++l) {
        // xq -> xa pair, xkv -> xb pair
        ln_dual_kernel<<<M_ / 4, 256, 0, stream>>>(
            h, xa_h, xa_l, xb_h, xb_l, ln1_g + l * H_, ln1_b + l * H_,
            ln1a_g + l * H_, ln1a_b + l * H_);

        // fused kv = per-head-LN( xkv @ [Wk;Wv] ) -> kv pair [M,512]
        gemm_split<4, 128, 2><<<dim3(512 / 128, M_ / 128), 256, 0, stream>>>(
            xb_h, xb_l, w_kvh + (size_t)l * 131072, w_kvl + (size_t)l * 131072,
            nullptr, kv_h, kv_l, nullptr, nullptr,
            lng + l * 512, lnb + l * 512, M_, 512, H_, 0);

        // ctx partials; compose1 (fused reduce) ; compose2
        ctx_partial_kernel<<<dim3(64, 8), 256, 0, stream>>>(kv_h, kv_l, ctxp);
        compose1_kernel<<<64, 256, 0, stream>>>(ctxp, Wo + (size_t)l * 65536, Gbuf);
        compose2_kernel<<<dim3(8, 16), 256, 0, stream>>>(Wq + (size_t)l * 65536, Gbuf, f_h, f_l);

        // h += xq @ F[batch] + bo   (TERMS=2, BN=64: 1024-block grid)
        gemm_split<2, 64, 2><<<dim3(256 / 64, M_ / 128), 256, 0, stream>>>(
            xa_h, xa_l, f_h, f_l, h, nullptr, nullptr, bo + l * H_, nullptr,
            nullptr, nullptr, M_, H_, H_, 65536);

        // y -> xa pair
        ln_dual_kernel<<<M_ / 4, 256, 0, stream>>>(
            h, xa_h, xa_l, nullptr, nullptr, ln2_g + l * H_, ln2_b + l * H_, nullptr, nullptr);

        // MLP in 2 half passes; hidden [M/2,1024] pair: hi in xb span, lo in kv_h span
        for (int half = 0; half < 2; ++half) {
            size_t ao = (size_t)half * (M_ / 2) * H_;
            gemm_split<1, 128, 3><<<dim3(DFF_ / 128, (M_ / 2) / 128), 256, 0, stream>>>(
                xa_h + ao, xa_l + ao, w_m1h + (size_t)l * 262144, w_m1l + (size_t)l * 262144,
                nullptr, xb_h, kv_h, mlp_b1 + (size_t)l * DFF_, nullptr,
                nullptr, nullptr, M_ / 2, DFF_, H_, 0);
            gemm_split<2, 64, 3><<<dim3(256 / 64, (M_ / 2) / 128), 256, 0, stream>>>(
                xb_h, kv_h, w_m2h + (size_t)l * 262144, w_m2l + (size_t)l * 262144,
                h + ao, nullptr, nullptr, mlp_b2 + (size_t)l * H_, nullptr,
                nullptr, nullptr, M_ / 2, H_, DFF_, 0);
        }
    }

    final_kernel<<<M_ / 4, 256, 0, stream>>>(
        h, ln3_g, ln3_b, out_W, out_b, (float*)d_out);
}

// Round 20
// 1996.533 us; speedup vs baseline: 1.0404x; 1.0010x over previous
//
#include <hip/hip_runtime.h>
#include <cmath>

#define B_    8
#define INS_  32
#define OUTS_ 64
#define REF_  8
#define H_    256
#define NH_   8
#define DH_   32
#define NL_   6
#define DFF_  1024
#define N_    4096
#define M_    (B_*N_)      // 32768 rows
#define BUF   8388608ull   // M*H elements

typedef unsigned short u16;
typedef unsigned int   u32;
typedef __attribute__((ext_vector_type(8))) short  bf16x8;
typedef __attribute__((ext_vector_type(4))) float  f32x4;
typedef __attribute__((ext_vector_type(4))) unsigned short u16x4;

struct bfpair { u16 hi, lo; };

__device__ __forceinline__ float gelu_f(float x){
    return 0.5f * x * (1.0f + erff(x * 0.70710678118654752f));
}
__device__ __forceinline__ u16 f2b(float f){
    union { float f; u32 u; } v; v.f = f;
    u32 r = v.u + 0x7fffu + ((v.u >> 16) & 1u);
    return (u16)(r >> 16);
}
__device__ __forceinline__ float b2f(u16 b){
    union { u32 u; float f; } v; v.u = ((u32)b) << 16;
    return v.f;
}
__device__ __forceinline__ bfpair fsplit(float x){
    bfpair p;
    p.hi = f2b(x);
    p.lo = f2b(x - b2f(p.hi));
    return p;
}

// ---------------------------------------------------------------------------
// Weight convert+transpose+split: out[l*lstride + n*Kpad + k] = split(in[l][k][n])
// ---------------------------------------------------------------------------
__global__ __launch_bounds__(256) void tconv_kernel(const float* __restrict__ in,
                                                    u16* __restrict__ oh,
                                                    u16* __restrict__ ol,
                                                    int K, int N, int Kpad, int nl,
                                                    int lstride)
{
    int idx = blockIdx.x * 256 + threadIdx.x;
    int per = N * Kpad;
    if (idx >= nl * per) return;
    int l = idx / per;
    int rem = idx - l * per;
    int n = rem / Kpad;
    int k = rem - n * Kpad;
    float v = (k < K) ? in[(size_t)l * K * N + (size_t)k * N + n] : 0.0f;
    bfpair p = fsplit(v);
    size_t o = (size_t)l * lstride + (size_t)n * Kpad + k;
    oh[o] = p.hi; ol[o] = p.lo;
}

// ---------------------------------------------------------------------------
// Concatenate kn||vn affines per layer -> [NL][512] fp32
// ---------------------------------------------------------------------------
__global__ __launch_bounds__(256) void lnfold_kernel(const float* __restrict__ kg,
                                                     const float* __restrict__ kb,
                                                     const float* __restrict__ vg,
                                                     const float* __restrict__ vb,
                                                     float* __restrict__ lng,
                                                     float* __restrict__ lnb)
{
    int idx = blockIdx.x * 256 + threadIdx.x;
    if (idx >= NL_ * 512) return;
    int l = idx >> 9, c = idx & 511;
    if (c < 256) { lng[idx] = kg[l * 256 + c];       lnb[idx] = kb[l * 256 + c]; }
    else         { lng[idx] = vg[l * 256 + c - 256]; lnb[idx] = vb[l * 256 + c - 256]; }
}

// ---------------------------------------------------------------------------
// fx builder -> split bf16 [M, 128] (cols 0..64 real, rest zero; K padded for BK=64)
// ---------------------------------------------------------------------------
__global__ __launch_bounds__(256) void fx_kernel(const float* __restrict__ x,
                                                 u16* __restrict__ fh,
                                                 u16* __restrict__ fl)
{
    int idx = blockIdx.x * 256 + threadIdx.x;
    const int total = M_ * 128;
    if (idx >= total) return;
    int f   = idx & 127;
    int row = idx >> 7;
    int n   = row % N_;
    int b   = row / N_;
    int gi = n >> 6, gj = n & 63;
    float v = 0.0f;
    if (f == 0) {
        float ci = gi * (31.0f / 63.0f);
        float cj = gj * (31.0f / 63.0f);
        int i0 = (int)floorf(ci); int i1 = min(i0 + 1, 31);
        int j0 = (int)floorf(cj); int j1 = min(j0 + 1, 31);
        float wi = ci - (float)i0, wj = cj - (float)j0;
        const float* xb = x + (size_t)b * INS_ * INS_ * 3 + 2;  // channel 2
        float v00 = xb[(i0 * 32 + j0) * 3];
        float v01 = xb[(i0 * 32 + j1) * 3];
        float v10 = xb[(i1 * 32 + j0) * 3];
        float v11 = xb[(i1 * 32 + j1) * 3];
        float r0 = v00 * (1.0f - wi) + v10 * wi;
        float r1 = v01 * (1.0f - wi) + v11 * wi;
        v = r0 * (1.0f - wj) + r1 * wj;
    } else if (f < 65) {
        int r = f - 1;
        int ri = r >> 3, rj = r & 7;
        float dx = gi * (1.0f / 63.0f) - ri * (1.0f / 7.0f);
        float dy = gj * (1.0f / 63.0f) - rj * (1.0f / 7.0f);
        v = sqrtf(dx * dx + dy * dy);
    }
    bfpair p = fsplit(v);
    fh[idx] = p.hi; fl[idx] = p.lo;
}

// ---------------------------------------------------------------------------
// Split-bf16 MFMA GEMM, BK=64 single-buffer K-loop + XOR bank swizzle:
// LDS written linearly by global_load_lds, GLOBAL source column pre-swizzled
// (ch ^= row&7, 16B granules); reads apply the same XOR -> identical data
// to MFMA (bit-identical), bank conflicts eliminated (verified R18: 6.3M->0).
// TERMS=3: hi*hi + lo*hi + hi*lo (~fp32).  TERMS=2: hi*hi + lo*hi.
// EPI: 0 = split store, 1 = gelu->split store, 2 = f32 +=, 3 = f32 store +b2,
//      4 = fused per-head LN (DH=32) -> split store (kv path; BN=128 only).
// bstride: elements to advance Bh/Bl per 4096 A-rows (batched B); 0 = shared.
// XCD-aware chunked block swizzle (all grids divisible by 8). K % 64 == 0.
// ---------------------------------------------------------------------------
template<int EPI, int BN, int TERMS>
__global__ __launch_bounds__(256) void gemm_split(const u16* __restrict__ Ah,
                                                  const u16* __restrict__ Al,
                                                  const u16* __restrict__ Bh,
                                                  const u16* __restrict__ Bl,
                                                  float* __restrict__ Cf,
                                                  u16* __restrict__ Ch,
                                                  u16* __restrict__ Cl,
                                                  const float* __restrict__ bias,
                                                  const float* __restrict__ bias2,
                                                  const float* __restrict__ lng,
                                                  const float* __restrict__ lnb,
                                                  int M, int Nn, int K, int bstride)
{
    constexpr int NREP = BN / 32;           // frags per wave in N
    __shared__ u16 AsH[128 * 64];
    __shared__ u16 BsH[BN * 64];
    __shared__ u16 AsL[TERMS >= 2 ? 128 * 64 : 1];
    __shared__ u16 BsL[TERMS == 3 ? BN * 64 : 1];
    const int tid = threadIdx.x;
    const int nwgx = gridDim.x;
    const int nwg  = nwgx * gridDim.y;
    const int bid  = blockIdx.y * nwgx + blockIdx.x;
    const int swz  = (bid & 7) * (nwg >> 3) + (bid >> 3);
    const int bm = (swz / nwgx) * 128;
    const int bn = (swz % nwgx) * BN;
    const u16* BhB = Bh + (size_t)(bm >> 12) * bstride;
    const u16* BlB = Bl + (size_t)(bm >> 12) * bstride;
    const int l  = tid & 63;
    const int w  = tid >> 6;
    const int wr = w >> 1, wc = w & 1;
    const int lrow = l & 15;
    const int kh   = l >> 4;       // 0..3
    const int rx   = lrow & 7;     // fragment-row swizzle key

    auto stage = [&](int k0) {
        #pragma unroll
        for (int i = 0; i < 4; ++i) {       // A tile: 128 rows x 64 k
            int L = i * 256 + tid;
            int row = L >> 3, ch = L & 7;
            int chs = ch ^ (row & 7);       // pre-swizzled source column
            size_t goffA = (size_t)(bm + row) * K + k0 + chs * 8;
            __builtin_amdgcn_global_load_lds(
                (const __attribute__((address_space(1))) void*)(Ah + goffA),
                (__attribute__((address_space(3))) void*)(AsH + L * 8), 16, 0, 0);
            if constexpr (TERMS >= 2)
                __builtin_amdgcn_global_load_lds(
                    (const __attribute__((address_space(1))) void*)(Al + goffA),
                    (__attribute__((address_space(3))) void*)(AsL + L * 8), 16, 0, 0);
        }
        #pragma unroll
        for (int i = 0; i < BN / 32; ++i) { // B tile: BN rows x 64 k
            int L = i * 256 + tid;
            int row = L >> 3, ch = L & 7;
            int chs = ch ^ (row & 7);
            size_t goffB = (size_t)(bn + row) * K + k0 + chs * 8;
            __builtin_amdgcn_global_load_lds(
                (const __attribute__((address_space(1))) void*)(BhB + goffB),
                (__attribute__((address_space(3))) void*)(BsH + L * 8), 16, 0, 0);
            if constexpr (TERMS == 3)
                __builtin_amdgcn_global_load_lds(
                    (const __attribute__((address_space(1))) void*)(BlB + goffB),
                    (__attribute__((address_space(3))) void*)(BsL + L * 8), 16, 0, 0);
        }
    };

    f32x4 acc[4][NREP];
    #pragma unroll
    for (int m = 0; m < 4; ++m)
        #pragma unroll
        for (int n = 0; n < NREP; ++n)
            acc[m][n] = (f32x4){0.0f, 0.0f, 0.0f, 0.0f};

    const int nk = K >> 6;
    for (int t = 0; t < nk; ++t) {
        stage(t << 6);
        __syncthreads();
        #pragma unroll
        for (int kk = 0; kk < 2; ++kk) {
            const int csw = (kk * 4 + kh) ^ rx;     // swizzled read slot
            bf16x8 afh[4], afl[4], bfh[NREP], bfl[NREP];
            #pragma unroll
            for (int m = 0; m < 4; ++m) {
                int off = (wr * 64 + m * 16 + lrow) * 64 + csw * 8;
                afh[m] = *(const bf16x8*)(AsH + off);
                if constexpr (TERMS >= 2) afl[m] = *(const bf16x8*)(AsL + off);
            }
            #pragma unroll
            for (int n = 0; n < NREP; ++n) {
                int off = (wc * (BN / 2) + n * 16 + lrow) * 64 + csw * 8;
                bfh[n] = *(const bf16x8*)(BsH + off);
                if constexpr (TERMS == 3) bfl[n] = *(const bf16x8*)(BsL + off);
            }
            #pragma unroll
            for (int m = 0; m < 4; ++m)
                #pragma unroll
                for (int n = 0; n < NREP; ++n) {
                    acc[m][n] = __builtin_amdgcn_mfma_f32_16x16x32_bf16(afh[m], bfh[n], acc[m][n], 0, 0, 0);
                    if constexpr (TERMS >= 2)
                        acc[m][n] = __builtin_amdgcn_mfma_f32_16x16x32_bf16(afl[m], bfh[n], acc[m][n], 0, 0, 0);
                    if constexpr (TERMS == 3)
                        acc[m][n] = __builtin_amdgcn_mfma_f32_16x16x32_bf16(afh[m], bfl[n], acc[m][n], 0, 0, 0);
                }
        }
        if (t + 1 < nk) __syncthreads();    // release LDS for next stage
    }

    const int row0 = bm + wr * 64;
    const int col0 = bn + wc * (BN / 2);

    if constexpr (EPI == 4) {
        // fused per-head LayerNorm over DH=32 (stats via 16-lane shfl groups)
        #pragma unroll
        for (int m = 0; m < 4; ++m) {
            #pragma unroll
            for (int j = 0; j < 4; ++j) {
                int r = row0 + m * 16 + kh * 4 + j;
                #pragma unroll
                for (int hp = 0; hp < NREP / 2; ++hp) {
                    float a0 = acc[m][2 * hp + 0][j];
                    float a1 = acc[m][2 * hp + 1][j];
                    float s = a0 + a1;
                    s += __shfl_xor(s, 1); s += __shfl_xor(s, 2);
                    s += __shfl_xor(s, 4); s += __shfl_xor(s, 8);
                    float mean = s * (1.0f / 32.0f);
                    float d0 = a0 - mean, d1 = a1 - mean;
                    float q = d0 * d0 + d1 * d1;
                    q += __shfl_xor(q, 1); q += __shfl_xor(q, 2);
                    q += __shfl_xor(q, 4); q += __shfl_xor(q, 8);
                    float rstd = rsqrtf(q * (1.0f / 32.0f) + 1e-5f);
                    #pragma unroll
                    for (int t = 0; t < 2; ++t) {
                        int n = 2 * hp + t;
                        int col = col0 + n * 16 + lrow;
                        float dd = t ? d1 : d0;
                        float o = dd * rstd * lng[col] + lnb[col];
                        bfpair p = fsplit(o);
                        size_t idx = (size_t)r * Nn + col;
                        Ch[idx] = p.hi; Cl[idx] = p.lo;
                    }
                }
            }
        }
        return;
    }

    #pragma unroll
    for (int m = 0; m < 4; ++m) {
        #pragma unroll
        for (int n = 0; n < NREP; ++n) {
            int col = col0 + n * 16 + lrow;
            float bv = bias ? bias[col] : 0.0f;
            if (EPI == 3) bv += bias2[col];
            #pragma unroll
            for (int j = 0; j < 4; ++j) {
                int r = row0 + m * 16 + kh * 4 + j;
                float v = acc[m][n][j] + bv;
                size_t idx = (size_t)r * Nn + col;
                if (EPI == 0) {
                    bfpair p = fsplit(v);
                    Ch[idx] = p.hi; Cl[idx] = p.lo;
                } else if (EPI == 1) {
                    bfpair p = fsplit(gelu_f(v));
                    Ch[idx] = p.hi; Cl[idx] = p.lo;
                } else if (EPI == 2) {
                    Cf[idx] += v;
                } else {
                    Cf[idx] = v;
                }
            }
        }
    }
}

// ---------------------------------------------------------------------------
// Dual LayerNorm over H=256 (fp32 in, split bf16 out). o2h==nullptr -> single.
// ---------------------------------------------------------------------------
__global__ __launch_bounds__(256) void ln_dual_kernel(const float* __restrict__ h,
                                                      u16* __restrict__ o1h,
                                                      u16* __restrict__ o1l,
                                                      u16* __restrict__ o2h,
                                                      u16* __restrict__ o2l,
                                                      const float* __restrict__ g1,
                                                      const float* __restrict__ b1,
                                                      const float* __restrict__ g2,
                                                      const float* __restrict__ b2)
{
    int row  = blockIdx.x * 4 + (threadIdx.x >> 6);
    int lane = threadIdx.x & 63;
    const float4 v = ((const float4*)(h + (size_t)row * H_))[lane];
    float s = v.x + v.y + v.z + v.w;
    #pragma unroll
    for (int m = 1; m < 64; m <<= 1) s += __shfl_xor(s, m, 64);
    float mean = s * (1.0f / H_);
    float dx = v.x - mean, dy = v.y - mean, dz = v.z - mean, dw = v.w - mean;
    float sq = dx * dx + dy * dy + dz * dz + dw * dw;
    #pragma unroll
    for (int m = 1; m < 64; m <<= 1) sq += __shfl_xor(sq, m, 64);
    float rstd = rsqrtf(sq * (1.0f / H_) + 1e-5f);

    float4 G = ((const float4*)g1)[lane];
    float4 Bv = ((const float4*)b1)[lane];
    u16x4 oh, ol;
    bfpair p0 = fsplit(dx * rstd * G.x + Bv.x);
    bfpair p1 = fsplit(dy * rstd * G.y + Bv.y);
    bfpair p2 = fsplit(dz * rstd * G.z + Bv.z);
    bfpair p3 = fsplit(dw * rstd * G.w + Bv.w);
    oh.x = p0.hi; ol.x = p0.lo;
    oh.y = p1.hi; ol.y = p1.lo;
    oh.z = p2.hi; ol.z = p2.lo;
    oh.w = p3.hi; ol.w = p3.lo;
    ((u16x4*)(o1h + (size_t)row * H_))[lane] = oh;
    ((u16x4*)(o1l + (size_t)row * H_))[lane] = ol;
    if (o2h) {
        G = ((const float4*)g2)[lane];
        Bv = ((const float4*)b2)[lane];
        p0 = fsplit(dx * rstd * G.x + Bv.x);
        p1 = fsplit(dy * rstd * G.y + Bv.y);
        p2 = fsplit(dz * rstd * G.z + Bv.z);
        p3 = fsplit(dw * rstd * G.w + Bv.w);
        oh.x = p0.hi; ol.x = p0.lo;
        oh.y = p1.hi; ol.y = p1.lo;
        oh.z = p2.hi; ol.z = p2.lo;
        oh.w = p3.hi; ol.w = p3.lo;
        ((u16x4*)(o2h + (size_t)row * H_))[lane] = oh;
        ((u16x4*)(o2l + (size_t)row * H_))[lane] = ol;
    }
}

// ---------------------------------------------------------------------------
// ctx partials over fused kv buffer: ctxp[split][b*NH+h][32][32]
// 64-row LDS staging; per-thread row order unchanged.
// ---------------------------------------------------------------------------
__global__ __launch_bounds__(256) void ctx_partial_kernel(const u16* __restrict__ kvh,
                                                          const u16* __restrict__ kvl,
                                                          float* __restrict__ ctxp)
{
    int bh = blockIdx.x;            // 0..63
    int split = blockIdx.y;         // 0..7
    int b = bh >> 3, hd = bh & 7;
    __shared__ float kc[64][32], vc[64][32];
    int tid = threadIdx.x;
    int d  = tid >> 3;
    int e0 = (tid & 7) * 4;
    float a0 = 0, a1 = 0, a2 = 0, a3 = 0;
    int nbase = split * 512;
    for (int it = 0; it < 8; ++it) {
        #pragma unroll
        for (int i = 0; i < 8; ++i) {
            int elem = i * 256 + tid;
            int row = elem >> 5, col = elem & 31;
            size_t off = ((size_t)(b * N_ + nbase + it * 64 + row)) * 512 + hd * 32 + col;
            kc[row][col] = b2f(kvh[off]) + b2f(kvl[off]);
            vc[row][col] = b2f(kvh[off + 256]) + b2f(kvl[off + 256]);
        }
        __syncthreads();
        #pragma unroll
        for (int r = 0; r < 64; ++r) {
            float kd = kc[r][d];
            a0 += kd * vc[r][e0 + 0];
            a1 += kd * vc[r][e0 + 1];
            a2 += kd * vc[r][e0 + 2];
            a3 += kd * vc[r][e0 + 3];
        }
        __syncthreads();
    }
    float* out = ctxp + ((size_t)(split * 64 + bh)) * 1024 + d * 32 + e0;
    out[0] = a0; out[1] = a1; out[2] = a2; out[3] = a3;
}

// ---------------------------------------------------------------------------
// compose1 (fused ctx-reduce): G[b][hd*32+d][j] =
//   sum_e ( (1/N) * sum_sp ctxp[sp][b*8+hd][d][e] ) * Wo[hd*32+e][j]
// ---------------------------------------------------------------------------
__global__ __launch_bounds__(256) void compose1_kernel(const float* __restrict__ ctxp,
                                                       const float* __restrict__ Wo,
                                                       float* __restrict__ G)
{
    int b  = blockIdx.x >> 3;
    int hd = blockIdx.x & 7;
    __shared__ float cl[32][32];
    __shared__ float wl[32][256];
    int tid = threadIdx.x;
    {
        const float* src = ctxp + ((size_t)(b * 8 + hd)) * 1024;
        #pragma unroll
        for (int i = 0; i < 4; ++i) {
            float s = 0.0f;
            #pragma unroll
            for (int sp = 0; sp < 8; ++sp)
                s += src[(size_t)sp * 65536 + tid + 256 * i];
            ((float*)cl)[tid + 256 * i] = s * (1.0f / N_);
        }
        #pragma unroll
        for (int i = 0; i < 32; ++i)
            wl[i][tid] = Wo[(size_t)(hd * 32 + i) * 256 + tid];
    }
    __syncthreads();
    int j = tid;
    for (int d = 0; d < 32; ++d) {
        float s = 0.0f;
        #pragma unroll
        for (int e = 0; e < 32; ++e) s += cl[d][e] * wl[e][j];
        G[((size_t)b * 256 + hd * 32 + d) * 256 + j] = s;
    }
}

// ---------------------------------------------------------------------------
// compose2: F_t[b][j][i] = split( sum_m Wq[i][m] * G[b][m][j] )
// ---------------------------------------------------------------------------
__global__ __launch_bounds__(256) void compose2_kernel(const float* __restrict__ Wq,
                                                       const float* __restrict__ G,
                                                       u16* __restrict__ fh,
                                                       u16* __restrict__ fl)
{
    int b  = blockIdx.x;
    int jg = blockIdx.y;
    __shared__ float Gs[16][256];           // [jj][m]
    int tid = threadIdx.x;
    #pragma unroll
    for (int jj = 0; jj < 16; ++jj)
        Gs[jj][tid] = G[(size_t)b * 65536 + (size_t)tid * 256 + jg * 16 + jj];
    __syncthreads();
    int i = tid;
    float acc[16];
    #pragma unroll
    for (int jj = 0; jj < 16; ++jj) acc[jj] = 0.0f;
    for (int m = 0; m < 256; ++m) {
        float wv = Wq[(size_t)i * 256 + m];
        #pragma unroll
        for (int jj = 0; jj < 16; ++jj) acc[jj] += wv * Gs[jj][m];
    }
    #pragma unroll
    for (int jj = 0; jj < 16; ++jj) {
        bfpair p = fsplit(acc[jj]);
        size_t off = (size_t)b * 65536 + (size_t)(jg * 16 + jj) * 256 + i;
        fh[off] = p.hi; fl[off] = p.lo;
    }
}

// ---------------------------------------------------------------------------
// Final: out[row] = LN(h[row]) . out_W + out_b
// ---------------------------------------------------------------------------
__global__ __launch_bounds__(256) void final_kernel(const float* __restrict__ h,
                                                    const float* __restrict__ g,
                                                    const float* __restrict__ bb,
                                                    const float* __restrict__ W,
                                                    const float* __restrict__ ob,
                                                    float* __restrict__ out)
{
    int row  = blockIdx.x * 4 + (threadIdx.x >> 6);
    int lane = threadIdx.x & 63;
    const float4 v = ((const float4*)(h + (size_t)row * H_))[lane];
    float s = v.x + v.y + v.z + v.w;
    #pragma unroll
    for (int m = 1; m < 64; m <<= 1) s += __shfl_xor(s, m, 64);
    float mean = s * (1.0f / H_);
    float dx = v.x - mean, dy = v.y - mean, dz = v.z - mean, dw = v.w - mean;
    float sq = dx * dx + dy * dy + dz * dz + dw * dw;
    #pragma unroll
    for (int m = 1; m < 64; m <<= 1) sq += __shfl_xor(sq, m, 64);
    float rstd = rsqrtf(sq * (1.0f / H_) + 1e-5f);
    float4 G = ((const float4*)g)[lane];
    float4 Bv = ((const float4*)bb)[lane];
    float4 Wv = ((const float4*)W)[lane];
    float s2 = (dx * rstd * G.x + Bv.x) * Wv.x
             + (dy * rstd * G.y + Bv.y) * Wv.y
             + (dz * rstd * G.z + Bv.z) * Wv.z
             + (dw * rstd * G.w + Bv.w) * Wv.w;
    #pragma unroll
    for (int m = 1; m < 64; m <<= 1) s2 += __shfl_xor(s2, m, 64);
    if (lane == 0) out[row] = s2 + ob[0];
}

// ---------------------------------------------------------------------------
extern "C" void kernel_launch(void* const* d_in, const int* in_sizes, int n_in,
                              void* d_out, int out_size, void* d_ws, size_t ws_size,
                              hipStream_t stream)
{
    const float* x        = (const float*)d_in[0];
    const float* pre_W1   = (const float*)d_in[1];
    const float* pre_b1   = (const float*)d_in[2];
    const float* pre_W2   = (const float*)d_in[3];
    const float* pre_b2   = (const float*)d_in[4];
    const float* placeholder = (const float*)d_in[5];
    const float* ln1_g    = (const float*)d_in[6];
    const float* ln1_b    = (const float*)d_in[7];
    const float* ln1a_g   = (const float*)d_in[8];
    const float* ln1a_b   = (const float*)d_in[9];
    const float* Wq       = (const float*)d_in[10];
    const float* Wk       = (const float*)d_in[11];
    const float* Wv       = (const float*)d_in[12];
    const float* Wo       = (const float*)d_in[13];
    const float* bo       = (const float*)d_in[14];
    const float* kn_g     = (const float*)d_in[15];
    const float* kn_b     = (const float*)d_in[16];
    const float* vn_g     = (const float*)d_in[17];
    const float* vn_b     = (const float*)d_in[18];
    const float* ln2_g    = (const float*)d_in[19];
    const float* ln2_b    = (const float*)d_in[20];
    const float* mlp_W1   = (const float*)d_in[21];
    const float* mlp_b1   = (const float*)d_in[22];
    const float* mlp_W2   = (const float*)d_in[23];
    const float* mlp_b2   = (const float*)d_in[24];
    const float* ln3_g    = (const float*)d_in[25];
    const float* ln3_b    = (const float*)d_in[26];
    const float* out_W    = (const float*)d_in[27];
    const float* out_b    = (const float*)d_in[28];

    // ---- workspace layout (~197 MB) ----
    float* ws   = (float*)d_ws;
    float* h    = ws;                       // [M,H] fp32
    float* ctxp = ws + BUF;                 // [8,64,32,32]
    float* Gbuf = ctxp + 524288;            // [8,256,256] fp32
    float* lng  = Gbuf + 524288;            // [NL,512]
    float* lnb  = lng + NL_ * 512;          // [NL,512]
    u16* ub = (u16*)(lnb + NL_ * 512);
    u16* xa_h = ub;                         // fx(128-wide) / xq / y (hi)
    u16* xa_l = xa_h + BUF;
    u16* xb_h = xa_l + BUF;                 // xkv; hid_h spans xb_h..xb_l
    u16* xb_l = xb_h + BUF;
    u16* kv_h = xb_l + BUF;                 // [M,512] hi; pre-hidden hi span
    u16* kv_l = kv_h + 2 * BUF;             // [M,512] lo; pre-hidden lo span
    u16* wt   = kv_l + 2 * BUF;
    u16* w_pre1h = wt;               u16* w_pre1l = w_pre1h + 65536;     // [512][128]
    u16* w_pre2h = w_pre1l + 65536;  u16* w_pre2l = w_pre2h + 131072;    // [256][512]
    u16* w_kvh = w_pre2l + 131072;   u16* w_kvl = w_kvh + 786432;        // 6x[512][256]
    u16* w_m1h = w_kvl + 786432;     u16* w_m1l = w_m1h + 1572864;       // 6x[1024][256]
    u16* w_m2h = w_m1l + 1572864;    u16* w_m2l = w_m2h + 1572864;       // 6x[256][1024]
    u16* f_h   = w_m2l + 1572864;    u16* f_l   = f_h + 524288;          // 8x[256][256]

    // ---- weight convert+transpose+split, LN-affine concat ----
    tconv_kernel<<<(512 * 128 + 255) / 256, 256, 0, stream>>>(pre_W1, w_pre1h, w_pre1l, 65, 512, 128, 1, 65536);
    tconv_kernel<<<(256 * 512 + 255) / 256, 256, 0, stream>>>(pre_W2, w_pre2h, w_pre2l, 512, 256, 512, 1, 131072);
    tconv_kernel<<<(6 * 65536 + 255) / 256, 256, 0, stream>>>(Wk, w_kvh, w_kvl, 256, 256, 256, 6, 131072);
    tconv_kernel<<<(6 * 65536 + 255) / 256, 256, 0, stream>>>(Wv, w_kvh + 65536, w_kvl + 65536, 256, 256, 256, 6, 131072);
    tconv_kernel<<<(6 * 262144 + 255) / 256, 256, 0, stream>>>(mlp_W1, w_m1h, w_m1l, 256, 1024, 256, 6, 262144);
    tconv_kernel<<<(6 * 262144 + 255) / 256, 256, 0, stream>>>(mlp_W2, w_m2h, w_m2l, 1024, 256, 1024, 6, 262144);
    lnfold_kernel<<<(NL_ * 512 + 255) / 256, 256, 0, stream>>>(kn_g, kn_b, vn_g, vn_b, lng, lnb);

    // ---- pre-stage (full M): fx -> gelu(fx@W1) -> @W2 + placeholder -> h ----
    fx_kernel<<<(M_ * 128 + 255) / 256, 256, 0, stream>>>(x, xa_h, xa_l);
    gemm_split<1, 128, 3><<<dim3(512 / 128, M_ / 128), 256, 0, stream>>>(
        xa_h, xa_l, w_pre1h, w_pre1l, nullptr, kv_h, kv_l,
        pre_b1, nullptr, nullptr, nullptr, M_, 512, 128, 0);
    gemm_split<3, 128, 3><<<dim3(256 / 128, M_ / 128), 256, 0, stream>>>(
        kv_h, kv_l, w_pre2h, w_pre2l, h, nullptr, nullptr,
        pre_b2, placeholder, nullptr, nullptr, M_, 256, 512, 0);

    for (int l = 0; l < NL_; ++l) {
        // xq -> xa pair, xkv -> xb pair
        ln_dual_kernel<<<M_ / 4, 256, 0, stream>>>(
            h, xa_h, xa_l, xb_h, xb_l, ln1_g + l * H_, ln1_b + l * H_,
            ln1a_g + l * H_, ln1a_b + l * H_);

        // fused kv = per-head-LN( xkv @ [Wk;Wv] ) -> kv pair [M,512]
        gemm_split<4, 128, 2><<<dim3(512 / 128, M_ / 128), 256, 0, stream>>>(
            xb_h, xb_l, w_kvh + (size_t)l * 131072, w_kvl + (size_t)l * 131072,
            nullptr, kv_h, kv_l, nullptr, nullptr,
            lng + l * 512, lnb + l * 512, M_, 512, H_, 0);

        // ctx partials; compose1 (fused reduce) ; compose2
        ctx_partial_kernel<<<dim3(64, 8), 256, 0, stream>>>(kv_h, kv_l, ctxp);
        compose1_kernel<<<64, 256, 0, stream>>>(ctxp, Wo + (size_t)l * 65536, Gbuf);
        compose2_kernel<<<dim3(8, 16), 256, 0, stream>>>(Wq + (size_t)l * 65536, Gbuf, f_h, f_l);

        // h += xq @ F[batch] + bo   (TERMS=2, BN=64: 1024-block grid)
        gemm_split<2, 64, 2><<<dim3(256 / 64, M_ / 128), 256, 0, stream>>>(
            xa_h, xa_l, f_h, f_l, h, nullptr, nullptr, bo + l * H_, nullptr,
            nullptr, nullptr, M_, H_, H_, 65536);

        // y -> xa pair
        ln_dual_kernel<<<M_ / 4, 256, 0, stream>>>(
            h, xa_h, xa_l, nullptr, nullptr, ln2_g + l * H_, ln2_b + l * H_, nullptr, nullptr);

        // MLP in 2 half passes; hidden [M/2,1024] pair: hi in xb span, lo in kv_h span
        for (int half = 0; half < 2; ++half) {
            size_t ao = (size_t)half * (M_ / 2) * H_;
            gemm_split<1, 128, 3><<<dim3(DFF_ / 128, (M_ / 2) / 128), 256, 0, stream>>>(
                xa_h + ao, xa_l + ao, w_m1h + (size_t)l * 262144, w_m1l + (size_t)l * 262144,
                nullptr, xb_h, kv_h, mlp_b1 + (size_t)l * DFF_, nullptr,
                nullptr, nullptr, M_ / 2, DFF_, H_, 0);
            gemm_split<2, 64, 3><<<dim3(256 / 64, (M_ / 2) / 128), 256, 0, stream>>>(
                xb_h, kv_h, w_m2h + (size_t)l * 262144, w_m2l + (size_t)l * 262144,
                h + ao, nullptr, nullptr, mlp_b2 + (size_t)l * H_, nullptr,
                nullptr, nullptr, M_ / 2, H_, DFF_, 0);
        }
    }

    final_kernel<<<M_ / 4, 256, 0, stream>>>(
        h, ln3_g, ln3_b, out_W, out_b, (float*)d_out);
}